// Round 7
// baseline (2341.438 us; speedup 1.0000x reference)
//
#include <hip/hip_runtime.h>

#define ALPHA 0.1f
#define FIN 128
#define HD 64
#define TD 10
#define SCAN_ELEMS 1024
#define CHUNK 16384           // nodes per LDS chunk (2^14)
#define SPLIT 16              // edge-slices per chunk

// ---------------- init: tmax=0 ----------------
__global__ __launch_bounds__(64) void k_init(unsigned* tmaxb) {
    if (threadIdx.x == 0) *tmaxb = 0u;
}

// ---------------- max(edge_time): block-reduced, 1 atomic per block ----------------
__global__ __launch_bounds__(256) void k_tmax(const float* __restrict__ t, unsigned* tmaxb, int E) {
    __shared__ unsigned sm[4];
    unsigned m = 0u;
    for (int i = blockIdx.x * 256 + threadIdx.x; i < E; i += gridDim.x * 256)
        m = max(m, __float_as_uint(t[i]));
    #pragma unroll
    for (int off = 32; off > 0; off >>= 1)
        m = max(m, (unsigned)__shfl_down((int)m, off, 64));
    if ((threadIdx.x & 63) == 0) sm[threadIdx.x >> 6] = m;
    __syncthreads();
    if (threadIdx.x == 0) {
        m = max(max(sm[0], sm[1]), max(sm[2], sm[3]));
        atomicMax(tmaxb, m);
    }
}

// ------ chunked LDS-privatized deg(row,decay-weighted) + hist(col) ------
// grid = NCHUNK*SPLIT blocks of 1024; block (c,b): chunk c, edge-slice b.
// Also writes ebuf[e] = decay (chunk-0 group covers all edges).
__global__ __launch_bounds__(1024) void k_deghist(const int* __restrict__ ei,
                                                  const float* __restrict__ t,
                                                  const unsigned* __restrict__ tmaxb,
                                                  float* __restrict__ ebuf,
                                                  float* __restrict__ privD,
                                                  int* __restrict__ privH,
                                                  int E, int N) {
    __shared__ float ldsD[CHUNK];   // 64 KiB
    __shared__ int   ldsH[CHUNK];   // 64 KiB
    int c = blockIdx.x / SPLIT;
    int b = blockIdx.x - c * SPLIT;
    int base = c * CHUNK;
    for (int i = threadIdx.x; i < CHUNK; i += 1024) { ldsD[i] = 0.f; ldsH[i] = 0; }
    __syncthreads();
    float tmax = __uint_as_float(*tmaxb);
    long long e0 = (long long)E * b / SPLIT;
    long long e1 = (long long)E * (b + 1) / SPLIT;
    for (long long e = e0 + threadIdx.x; e < e1; e += 1024) {
        int r  = ei[e];
        int cc = ei[E + e];
        float d = expf(-ALPHA * (tmax - t[e]));
        if (c == 0) ebuf[e] = d;
        unsigned rr = (unsigned)(r - base);
        if (rr < CHUNK) atomicAdd(&ldsD[rr], d);
        unsigned cr = (unsigned)(cc - base);
        if (cr < CHUNK) atomicAdd(&ldsH[cr], 1);
    }
    __syncthreads();
    float* pd = privD + ((size_t)c * SPLIT + b) * CHUNK;
    int*   ph = privH + ((size_t)c * SPLIT + b) * CHUNK;
    for (int i = threadIdx.x; i < CHUNK; i += 1024) { pd[i] = ldsD[i]; ph[i] = ldsH[i]; }
}

// ------ reduce SPLIT private copies -> deg, hist; privH -> per-slice EXCLUSIVE prefix ------
__global__ __launch_bounds__(256) void k_deghist_red(const float* __restrict__ privD,
                                                     int* __restrict__ privH,
                                                     float* __restrict__ deg,
                                                     int* __restrict__ hist, int N) {
    int n = blockIdx.x * 256 + threadIdx.x;
    if (n >= N) return;
    int c = n >> 14;              // /CHUNK
    int i = n & (CHUNK - 1);
    const float* pd = privD + ((size_t)c * SPLIT) * CHUNK + i;
    int*         ph = privH + ((size_t)c * SPLIT) * CHUNK + i;
    float s = 0.f; int run = 0;
    #pragma unroll
    for (int b = 0; b < SPLIT; ++b) {
        s += pd[(size_t)b * CHUNK];
        int t = ph[(size_t)b * CHUNK];
        ph[(size_t)b * CHUNK] = run;       // exclusive prefix within node bucket
        run += t;
    }
    deg[n] = s;
    hist[n] = run;
}

// ---------------- in-place a = a>0 ? rsqrt(a) : 0 ----------------
__global__ __launch_bounds__(256) void k_rsqrt(float* a, int N) {
    int i = blockIdx.x * 256 + threadIdx.x;
    if (i >= N) return;
    float v = a[i];
    a[i] = v > 0.f ? rsqrtf(v) : 0.f;
}

// ---------------- scan phase A: per-block sum of 1024-elem hist chunk ----------------
__global__ __launch_bounds__(256) void k_scan_a(const int* __restrict__ hist,
                                                int* __restrict__ bsum, int N) {
    __shared__ int sm[4];
    int base = blockIdx.x * SCAN_ELEMS + threadIdx.x * 4;
    int s = 0;
    if (base + 3 < N) {
        int4 v = *(const int4*)(hist + base);
        s = v.x + v.y + v.z + v.w;
    } else {
        for (int i = base; i < N && i < base + 4; ++i) s += hist[i];
    }
    #pragma unroll
    for (int off = 32; off > 0; off >>= 1) s += __shfl_down(s, off, 64);
    if ((threadIdx.x & 63) == 0) sm[threadIdx.x >> 6] = s;
    __syncthreads();
    if (threadIdx.x == 0) bsum[blockIdx.x] = sm[0] + sm[1] + sm[2] + sm[3];
}

// ------- scan phase B: 1 block scans <=1024 partials; writes rowptr[N]=total -------
__global__ __launch_bounds__(1024) void k_scan_b(const int* __restrict__ bsum,
                                                 int* __restrict__ boff,
                                                 int NB, int* __restrict__ rowptrN) {
    __shared__ int part[1024];
    int tid = threadIdx.x;
    int v = (tid < NB) ? bsum[tid] : 0;
    part[tid] = v;
    __syncthreads();
    for (int d = 1; d < 1024; d <<= 1) {
        int t = (tid >= d) ? part[tid - d] : 0;
        __syncthreads();
        part[tid] += t;
        __syncthreads();
    }
    if (tid < NB) boff[tid] = part[tid] - v;
    if (tid == 1023) *rowptrN = part[1023];
}

// ------- scan phase C: block-local scan + block offset -> rowptr ----------
__global__ __launch_bounds__(256) void k_scan_c(const int* __restrict__ hist,
                                                const int* __restrict__ boff,
                                                int* __restrict__ rowptr, int N) {
    __shared__ int part[256];
    int base = blockIdx.x * SCAN_ELEMS + threadIdx.x * 4;
    int vv[4] = {0, 0, 0, 0};
    if (base + 3 < N) {
        int4 v = *(const int4*)(hist + base);
        vv[0] = v.x; vv[1] = v.y; vv[2] = v.z; vv[3] = v.w;
    } else {
        for (int i = 0; i < 4; ++i) if (base + i < N) vv[i] = hist[base + i];
    }
    int s = vv[0] + vv[1] + vv[2] + vv[3];
    part[threadIdx.x] = s;
    __syncthreads();
    for (int d = 1; d < 256; d <<= 1) {
        int t = (threadIdx.x >= d) ? part[threadIdx.x - d] : 0;
        __syncthreads();
        part[threadIdx.x] += t;
        __syncthreads();
    }
    int run = boff[blockIdx.x] + part[threadIdx.x] - s;
    int pp[4];
    pp[0] = run;
    pp[1] = pp[0] + vv[0];
    pp[2] = pp[1] + vv[1];
    pp[3] = pp[2] + vv[2];
    if (base + 3 < N) {
        *(int4*)(rowptr + base) = make_int4(pp[0], pp[1], pp[2], pp[3]);
    } else {
        for (int i = 0; i < 4; ++i)
            if (base + i < N) rowptr[base + i] = pp[i];
    }
}

// ------- chunked CSR fill, NO device atomics: LDS cursor owned per (chunk,slice) -------
// cursor[i] = rowptr[base+i] + privH_prefix[(c,b)][i]; writes land in chunk's
// contiguous CSR segment (L2-local). CSR weight is RAW ew (dinv2 folded into k_agg).
__global__ __launch_bounds__(1024) void k_fill(const int* __restrict__ ei,
                                               const float* __restrict__ ebuf,
                                               const float* __restrict__ dinv,
                                               const int* __restrict__ rowptr,
                                               const int* __restrict__ privH,
                                               int* __restrict__ sidx,
                                               float* __restrict__ sw,
                                               int E, int N) {
    __shared__ int cur[CHUNK];      // 64 KiB
    int c = blockIdx.x / SPLIT;
    int b = blockIdx.x - c * SPLIT;
    int base = c * CHUNK;
    int lim = min(CHUNK, N - base);
    const int* ph = privH + ((size_t)c * SPLIT + b) * CHUNK;
    for (int i = threadIdx.x; i < lim; i += 1024)
        cur[i] = rowptr[base + i] + ph[i];
    __syncthreads();
    long long e0 = (long long)E * b / SPLIT;
    long long e1 = (long long)E * (b + 1) / SPLIT;
    for (long long e = e0 + threadIdx.x; e < e1; e += 1024) {
        int cc = ei[E + e];
        unsigned cr = (unsigned)(cc - base);
        if (cr < (unsigned)lim) {
            int r = ei[e];
            int pos = atomicAdd(&cur[cr], 1);   // LDS atomic, block-exclusive
            sidx[pos] = r;
            sw[pos]   = dinv[r] * ebuf[e] * dinv[cc];
        }
    }
}

// ------- deg2[c] = 1 + segment_sum(sw over bucket c)  (no atomics) -------
__global__ __launch_bounds__(256) void k_deg2(const int* __restrict__ rowptr,
                                              const float* __restrict__ sw,
                                              float* __restrict__ deg2, int N) {
    int n = blockIdx.x * 256 + threadIdx.x;
    if (n >= N) return;
    int s = rowptr[n], e = rowptr[n + 1];
    float a = 1.f;
    for (int p = s; p < e; ++p) a += sw[p];
    deg2[n] = a;
}

// -------- g1 = dinv2 * (x @ W1): K split in 2 halves, Wreg[64], acc[16]/wave --------
__global__ __launch_bounds__(256) void k_mm1(const float* __restrict__ x,
                                             const float* __restrict__ W1,
                                             const float* __restrict__ dinv2,
                                             float* __restrict__ gbuf, int N) {
    __shared__ float xl[64 * FIN];  // 32 KiB
    int tid  = threadIdx.x;
    int lane = tid & 63;
    int wv   = tid >> 6;
    int tile0 = blockIdx.x * 64;
    if (tile0 >= N) return;
    int nrow = min(64, N - tile0);
    const float4* gx = (const float4*)(x + (size_t)tile0 * FIN);
    float4* lx = (float4*)xl;
    int nv = nrow * (FIN / 4);
    for (int i = tid; i < nv; i += 256) lx[i] = gx[i];
    __syncthreads();
    float acc[16];
    #pragma unroll
    for (int i = 0; i < 16; ++i) acc[i] = 0.f;
    int r0 = wv * 16;
    #pragma unroll
    for (int kk = 0; kk < 2; ++kk) {
        float Wreg[64];
        #pragma unroll
        for (int k = 0; k < 64; ++k) Wreg[k] = W1[(kk * 64 + k) * HD + lane];
        #pragma unroll
        for (int rr = 0; rr < 16; ++rr) {
            const float4* xr = (const float4*)(xl + (r0 + rr) * FIN + kk * 64);
            float a0 = 0.f, a1 = 0.f, a2 = 0.f, a3 = 0.f;
            #pragma unroll
            for (int k4 = 0; k4 < 16; ++k4) {
                float4 v = xr[k4];
                a0 += v.x * Wreg[4 * k4 + 0];
                a1 += v.y * Wreg[4 * k4 + 1];
                a2 += v.z * Wreg[4 * k4 + 2];
                a3 += v.w * Wreg[4 * k4 + 3];
            }
            acc[rr] += (a0 + a1) + (a2 + a3);
        }
    }
    #pragma unroll
    for (int rr = 0; rr < 16; ++rr) {
        int r = r0 + rr;
        if (r < nrow) {
            float sn = dinv2[tile0 + r];
            gbuf[(size_t)(tile0 + r) * HD + lane] = sn * acc[rr];
        }
    }
}

// -- g2 = dinv2 * (relu(agg+b1) @ W2): W col in regs, relu fused into LDS stage --
__global__ __launch_bounds__(256) void k_mm2(const float* __restrict__ agg,
                                             const float* __restrict__ b1,
                                             const float* __restrict__ W2,
                                             const float* __restrict__ dinv2,
                                             float* __restrict__ gbuf, int N) {
    __shared__ float xl[128 * HD];  // 32 KiB
    int tid  = threadIdx.x;
    int lane = tid & 63;
    int wv   = tid >> 6;
    float Wreg[HD];
    #pragma unroll
    for (int k = 0; k < HD; ++k) Wreg[k] = W2[k * HD + lane];
    float4 bb = ((const float4*)b1)[tid & 15];
    int tile0 = blockIdx.x * 128;
    if (tile0 >= N) return;
    int nrow = min(128, N - tile0);
    const float4* gx = (const float4*)(agg + (size_t)tile0 * HD);
    float4* lx = (float4*)xl;
    int nv = nrow * (HD / 4);
    for (int i = tid; i < nv; i += 256) {
        float4 v = gx[i];
        v.x = fmaxf(v.x + bb.x, 0.f);
        v.y = fmaxf(v.y + bb.y, 0.f);
        v.z = fmaxf(v.z + bb.z, 0.f);
        v.w = fmaxf(v.w + bb.w, 0.f);
        lx[i] = v;
    }
    __syncthreads();
    for (int r = wv; r < nrow; r += 4) {
        const float4* xr = (const float4*)(xl + r * HD);
        float a0 = 0.f, a1 = 0.f, a2 = 0.f, a3 = 0.f;
        #pragma unroll
        for (int k4 = 0; k4 < HD / 4; ++k4) {
            float4 v = xr[k4];
            a0 += v.x * Wreg[4 * k4 + 0];
            a1 += v.y * Wreg[4 * k4 + 1];
            a2 += v.z * Wreg[4 * k4 + 2];
            a3 += v.w * Wreg[4 * k4 + 3];
        }
        float sn = dinv2[tile0 + r];
        gbuf[(size_t)(tile0 + r) * HD + lane] = sn * ((a0 + a1) + (a2 + a3));
    }
}

// ------- CSR gather: agg[c] = dinv2[c]*( g[c] + sum_e ew[e]*g[src[e]] ) -------
__global__ __launch_bounds__(256) void k_agg(const int* __restrict__ rowptr,
                                             const int* __restrict__ sidx,
                                             const float* __restrict__ sw,
                                             const float* __restrict__ g,
                                             const float* __restrict__ dinv2,
                                             float* __restrict__ agg, int N) {
    int lane = threadIdx.x & 63;
    int node = (blockIdx.x * 256 + threadIdx.x) >> 6;
    if (node >= N) return;
    int s = rowptr[node];
    int e = rowptr[node + 1];
    float a0 = g[(size_t)node * HD + lane];
    float a1 = 0.f, a2 = 0.f, a3 = 0.f;
    int p = s;
    for (; p + 4 <= e; p += 4) {
        int  s0 = sidx[p + 0], s1 = sidx[p + 1], s2 = sidx[p + 2], s3 = sidx[p + 3];
        float w0 = sw[p + 0], w1 = sw[p + 1], w2 = sw[p + 2], w3 = sw[p + 3];
        a0 += w0 * g[(size_t)s0 * HD + lane];
        a1 += w1 * g[(size_t)s1 * HD + lane];
        a2 += w2 * g[(size_t)s2 * HD + lane];
        a3 += w3 * g[(size_t)s3 * HD + lane];
    }
    for (; p < e; ++p)
        a0 += sw[p] * g[(size_t)sidx[p] * HD + lane];
    agg[(size_t)node * HD + lane] = dinv2[node] * ((a0 + a1) + (a2 + a3));
}

// ---------------- out = relu(agg + b2) @ Wout + bout ----------------
__global__ __launch_bounds__(256) void k_out(const float* __restrict__ agg,
                                             const float* __restrict__ b2,
                                             const float* __restrict__ Wout,
                                             const float* __restrict__ bout,
                                             float* __restrict__ out, int N) {
    __shared__ float Wl[HD * TD];
    __shared__ float bl[HD];
    __shared__ float bo[TD];
    for (int i = threadIdx.x; i < HD * TD; i += 256) Wl[i] = Wout[i];
    if (threadIdx.x < HD) bl[threadIdx.x] = b2[threadIdx.x];
    if (threadIdx.x < TD) bo[threadIdx.x] = bout[threadIdx.x];
    __syncthreads();
    int idx = blockIdx.x * 256 + threadIdx.x;
    if (idx >= N * TD) return;
    int n = idx / TD;
    int t = idx - n * TD;
    const float* a = agg + (size_t)n * HD;
    float acc = bo[t];
    #pragma unroll 8
    for (int k = 0; k < HD; ++k)
        acc += fmaxf(a[k] + bl[k], 0.f) * Wl[k * TD + t];
    out[idx] = acc;
}

extern "C" void kernel_launch(void* const* d_in, const int* in_sizes, int n_in,
                              void* d_out, int out_size, void* d_ws, size_t ws_size,
                              hipStream_t stream) {
    const float* x    = (const float*)d_in[0];
    const int*   ei   = (const int*)d_in[1];   // harness passes integers as int32
    const float* et   = (const float*)d_in[2];
    const float* W1   = (const float*)d_in[3];
    const float* b1   = (const float*)d_in[4];
    const float* W2   = (const float*)d_in[5];
    const float* b2   = (const float*)d_in[6];
    const float* Wout = (const float*)d_in[7];
    const float* bout = (const float*)d_in[8];
    float*       out  = (float*)d_out;

    int N = in_sizes[0] / FIN;
    int E = in_sizes[2];
    int NCHUNK = (N + CHUNK - 1) / CHUNK;          // 7 for N=100K
    int NB = (N + SCAN_ELEMS - 1) / SCAN_ELEMS;    // scan blocks (98)

    // --- workspace layout, 256B-aligned regions ---
    char*  base = (char*)d_ws;
    size_t ofs  = 0;
    auto alloc = [&](size_t bytes) -> char* {
        char* p = base + ofs;
        ofs = (ofs + bytes + 255) & ~(size_t)255;
        return p;
    };
    unsigned* tmaxb  = (unsigned*)alloc(64);
    float*    ebuf   = (float*)alloc((size_t)E * 4);        // decay
    float*    deg    = (float*)alloc((size_t)N * 4);        // deg -> dinv
    float*    deg2   = (float*)alloc((size_t)N * 4);        // deg2 -> dinv2
    int*      hist   = (int*)alloc((size_t)N * 4);
    int*      rowptr = (int*)alloc((size_t)(N + 1) * 4);
    int*      bsum   = (int*)alloc((size_t)1024 * 4);
    int*      boff   = (int*)alloc((size_t)1024 * 4);
    size_t privBytes = (size_t)NCHUNK * SPLIT * CHUNK * 4;  // 7.34 MB
    size_t csrBytes  = ((size_t)E * 4 + 255) & ~(size_t)255;
    // privD dead after k_deghist_red -> alias with sidx
    char*  privA = alloc(privBytes > csrBytes ? privBytes : csrBytes);
    float* privD = (float*)privA;
    int*   sidx  = (int*)privA;
    int*   privH = (int*)alloc(privBytes);                  // persists through k_fill
    float* sw    = (float*)alloc(csrBytes);
    float* gbuf  = (float*)alloc((size_t)N * HD * 4);
    float* agg   = (float*)alloc((size_t)N * HD * 4);

    int bN  = (N + 255) / 256;
    int bT1 = (N + 63) / 64;
    int bT2 = (N + 127) / 128;
    int bWN = (N * HD + 255) / 256;

    k_init       <<<1,   64,  0, stream>>>(tmaxb);
    k_tmax       <<<256, 256, 0, stream>>>(et, tmaxb, E);
    k_deghist    <<<NCHUNK * SPLIT, 1024, 0, stream>>>(ei, et, tmaxb, ebuf, privD, privH, E, N);
    k_deghist_red<<<bN,  256, 0, stream>>>(privD, privH, deg, hist, N);
    k_rsqrt      <<<bN,  256, 0, stream>>>(deg, N);
    k_scan_a     <<<NB,  256, 0, stream>>>(hist, bsum, N);
    k_scan_b     <<<1,  1024, 0, stream>>>(bsum, boff, NB, rowptr + N);
    k_scan_c     <<<NB,  256, 0, stream>>>(hist, boff, rowptr, N);
    k_fill       <<<NCHUNK * SPLIT, 1024, 0, stream>>>(ei, ebuf, deg, rowptr, privH, sidx, sw, E, N);
    k_deg2       <<<bN,  256, 0, stream>>>(rowptr, sw, deg2, N);
    k_rsqrt      <<<bN,  256, 0, stream>>>(deg2, N);

    k_mm1        <<<bT1, 256, 0, stream>>>(x, W1, deg2, gbuf, N);
    k_agg        <<<bWN, 256, 0, stream>>>(rowptr, sidx, sw, gbuf, deg2, agg, N);
    k_mm2        <<<bT2, 256, 0, stream>>>(agg, b1, W2, deg2, gbuf, N);
    k_agg        <<<bWN, 256, 0, stream>>>(rowptr, sidx, sw, gbuf, deg2, agg, N);
    k_out        <<<(N * TD + 255) / 256, 256, 0, stream>>>(agg, b2, Wout, bout, out, N);
}

// Round 8
// 477.779 us; speedup vs baseline: 4.9007x; 4.9007x over previous
//
#include <hip/hip_runtime.h>

#define ALPHA 0.1f
#define FIN 128
#define HD 64
#define TD 10
#define SCAN_ELEMS 1024
#define CHUNK 16384           // nodes per LDS chunk (2^14)
#define SPLIT 16              // edge-slices per chunk

// ---------------- init: tmax=0 ----------------
__global__ __launch_bounds__(64) void k_init(unsigned* tmaxb) {
    if (threadIdx.x == 0) *tmaxb = 0u;
}

// ---------------- max(edge_time): block-reduced, 1 atomic per block ----------------
__global__ __launch_bounds__(256) void k_tmax(const float* __restrict__ t, unsigned* tmaxb, int E) {
    __shared__ unsigned sm[4];
    unsigned m = 0u;
    for (int i = blockIdx.x * 256 + threadIdx.x; i < E; i += gridDim.x * 256)
        m = max(m, __float_as_uint(t[i]));
    #pragma unroll
    for (int off = 32; off > 0; off >>= 1)
        m = max(m, (unsigned)__shfl_down((int)m, off, 64));
    if ((threadIdx.x & 63) == 0) sm[threadIdx.x >> 6] = m;
    __syncthreads();
    if (threadIdx.x == 0) {
        m = max(max(sm[0], sm[1]), max(sm[2], sm[3]));
        atomicMax(tmaxb, m);
    }
}

// ------ chunked LDS-privatized deg(row,decay-weighted) + hist(col) ------
__global__ __launch_bounds__(1024) void k_deghist(const int* __restrict__ ei,
                                                  const float* __restrict__ t,
                                                  const unsigned* __restrict__ tmaxb,
                                                  float* __restrict__ ebuf,
                                                  float* __restrict__ privD,
                                                  int* __restrict__ privH,
                                                  int E, int N) {
    __shared__ float ldsD[CHUNK];   // 64 KiB
    __shared__ int   ldsH[CHUNK];   // 64 KiB
    int c = blockIdx.x / SPLIT;
    int b = blockIdx.x - c * SPLIT;
    int base = c * CHUNK;
    for (int i = threadIdx.x; i < CHUNK; i += 1024) { ldsD[i] = 0.f; ldsH[i] = 0; }
    __syncthreads();
    float tmax = __uint_as_float(*tmaxb);
    long long e0 = (long long)E * b / SPLIT;
    long long e1 = (long long)E * (b + 1) / SPLIT;
    for (long long e = e0 + threadIdx.x; e < e1; e += 1024) {
        int r  = ei[e];
        int cc = ei[E + e];
        float d = expf(-ALPHA * (tmax - t[e]));
        if (c == 0) ebuf[e] = d;
        unsigned rr = (unsigned)(r - base);
        if (rr < CHUNK) atomicAdd(&ldsD[rr], d);
        unsigned cr = (unsigned)(cc - base);
        if (cr < CHUNK) atomicAdd(&ldsH[cr], 1);
    }
    __syncthreads();
    float* pd = privD + ((size_t)c * SPLIT + b) * CHUNK;
    int*   ph = privH + ((size_t)c * SPLIT + b) * CHUNK;
    for (int i = threadIdx.x; i < CHUNK; i += 1024) { pd[i] = ldsD[i]; ph[i] = ldsH[i]; }
}

// ------ reduce SPLIT private copies -> deg, hist; privH -> per-slice EXCLUSIVE prefix ------
__global__ __launch_bounds__(256) void k_deghist_red(const float* __restrict__ privD,
                                                     int* __restrict__ privH,
                                                     float* __restrict__ deg,
                                                     int* __restrict__ hist, int N) {
    int n = blockIdx.x * 256 + threadIdx.x;
    if (n >= N) return;
    int c = n >> 14;              // /CHUNK
    int i = n & (CHUNK - 1);
    const float* pd = privD + ((size_t)c * SPLIT) * CHUNK + i;
    int*         ph = privH + ((size_t)c * SPLIT) * CHUNK + i;
    float s = 0.f; int run = 0;
    #pragma unroll
    for (int b = 0; b < SPLIT; ++b) {
        s += pd[(size_t)b * CHUNK];
        int t = ph[(size_t)b * CHUNK];
        ph[(size_t)b * CHUNK] = run;       // exclusive prefix within node bucket
        run += t;
    }
    deg[n] = s;
    hist[n] = run;
}

// ---------------- in-place a = a>0 ? rsqrt(a) : 0 ----------------
__global__ __launch_bounds__(256) void k_rsqrt(float* a, int N) {
    int i = blockIdx.x * 256 + threadIdx.x;
    if (i >= N) return;
    float v = a[i];
    a[i] = v > 0.f ? rsqrtf(v) : 0.f;
}

// ---------------- scan phase A: per-block sum of 1024-elem hist chunk ----------------
__global__ __launch_bounds__(256) void k_scan_a(const int* __restrict__ hist,
                                                int* __restrict__ bsum, int N) {
    __shared__ int sm[4];
    int base = blockIdx.x * SCAN_ELEMS + threadIdx.x * 4;
    int s = 0;
    if (base + 3 < N) {
        int4 v = *(const int4*)(hist + base);
        s = v.x + v.y + v.z + v.w;
    } else {
        for (int i = base; i < N && i < base + 4; ++i) s += hist[i];
    }
    #pragma unroll
    for (int off = 32; off > 0; off >>= 1) s += __shfl_down(s, off, 64);
    if ((threadIdx.x & 63) == 0) sm[threadIdx.x >> 6] = s;
    __syncthreads();
    if (threadIdx.x == 0) bsum[blockIdx.x] = sm[0] + sm[1] + sm[2] + sm[3];
}

// ------- scan phase B: 1 block scans <=1024 partials; writes rowptr[N]=total -------
__global__ __launch_bounds__(1024) void k_scan_b(const int* __restrict__ bsum,
                                                 int* __restrict__ boff,
                                                 int NB, int* __restrict__ rowptrN) {
    __shared__ int part[1024];
    int tid = threadIdx.x;
    int v = (tid < NB) ? bsum[tid] : 0;
    part[tid] = v;
    __syncthreads();
    for (int d = 1; d < 1024; d <<= 1) {
        int t = (tid >= d) ? part[tid - d] : 0;
        __syncthreads();
        part[tid] += t;
        __syncthreads();
    }
    if (tid < NB) boff[tid] = part[tid] - v;
    if (tid == 1023) *rowptrN = part[1023];
}

// ------- scan phase C: block-local scan + block offset -> rowptr ----------
__global__ __launch_bounds__(256) void k_scan_c(const int* __restrict__ hist,
                                                const int* __restrict__ boff,
                                                int* __restrict__ rowptr, int N) {
    __shared__ int part[256];
    int base = blockIdx.x * SCAN_ELEMS + threadIdx.x * 4;
    int vv[4] = {0, 0, 0, 0};
    if (base + 3 < N) {
        int4 v = *(const int4*)(hist + base);
        vv[0] = v.x; vv[1] = v.y; vv[2] = v.z; vv[3] = v.w;
    } else {
        for (int i = 0; i < 4; ++i) if (base + i < N) vv[i] = hist[base + i];
    }
    int s = vv[0] + vv[1] + vv[2] + vv[3];
    part[threadIdx.x] = s;
    __syncthreads();
    for (int d = 1; d < 256; d <<= 1) {
        int t = (threadIdx.x >= d) ? part[threadIdx.x - d] : 0;
        __syncthreads();
        part[threadIdx.x] += t;
        __syncthreads();
    }
    int run = boff[blockIdx.x] + part[threadIdx.x] - s;
    int pp[4];
    pp[0] = run;
    pp[1] = pp[0] + vv[0];
    pp[2] = pp[1] + vv[1];
    pp[3] = pp[2] + vv[2];
    if (base + 3 < N) {
        *(int4*)(rowptr + base) = make_int4(pp[0], pp[1], pp[2], pp[3]);
    } else {
        for (int i = 0; i < 4; ++i)
            if (base + i < N) rowptr[base + i] = pp[i];
    }
}

// ------- chunked CSR fill, NO device atomics: LDS cursor owned per (chunk,slice) -------
__global__ __launch_bounds__(1024) void k_fill(const int* __restrict__ ei,
                                               const float* __restrict__ ebuf,
                                               const float* __restrict__ dinv,
                                               const int* __restrict__ rowptr,
                                               const int* __restrict__ privH,
                                               int* __restrict__ sidx,
                                               float* __restrict__ sw,
                                               int E, int N) {
    __shared__ int cur[CHUNK];      // 64 KiB
    int c = blockIdx.x / SPLIT;
    int b = blockIdx.x - c * SPLIT;
    int base = c * CHUNK;
    int lim = min(CHUNK, N - base);
    const int* ph = privH + ((size_t)c * SPLIT + b) * CHUNK;
    for (int i = threadIdx.x; i < lim; i += 1024)
        cur[i] = rowptr[base + i] + ph[i];
    __syncthreads();
    long long e0 = (long long)E * b / SPLIT;
    long long e1 = (long long)E * (b + 1) / SPLIT;
    for (long long e = e0 + threadIdx.x; e < e1; e += 1024) {
        int cc = ei[E + e];
        unsigned cr = (unsigned)(cc - base);
        if (cr < (unsigned)lim) {
            int r = ei[e];
            int pos = atomicAdd(&cur[cr], 1);   // LDS atomic, block-exclusive
            sidx[pos] = r;
            sw[pos]   = dinv[r] * ebuf[e] * dinv[cc];
        }
    }
}

// ------- deg2[c] = 1 + segment_sum(sw over bucket c)  (no atomics) -------
__global__ __launch_bounds__(256) void k_deg2(const int* __restrict__ rowptr,
                                              const float* __restrict__ sw,
                                              float* __restrict__ deg2, int N) {
    int n = blockIdx.x * 256 + threadIdx.x;
    if (n >= N) return;
    int s = rowptr[n], e = rowptr[n + 1];
    float a = 1.f;
    for (int p = s; p < e; ++p) a += sw[p];
    deg2[n] = a;
}

// -------- g1 = dinv2 * (x @ W1): W column in regs, x tile in LDS, 4 acc chains --------
// (round-6 verified version: VGPR 152, ~139 us; round-7 K-split spilled, reverted)
__global__ __launch_bounds__(256) void k_mm1(const float* __restrict__ x,
                                             const float* __restrict__ W1,
                                             const float* __restrict__ dinv2,
                                             float* __restrict__ gbuf, int N) {
    __shared__ float xl[64 * FIN];  // 32 KiB
    int tid  = threadIdx.x;
    int lane = tid & 63;
    int wv   = tid >> 6;
    float Wreg[FIN];
    #pragma unroll
    for (int k = 0; k < FIN; ++k) Wreg[k] = W1[k * HD + lane];
    int tile0 = blockIdx.x * 64;
    if (tile0 >= N) return;
    int nrow = min(64, N - tile0);
    const float4* gx = (const float4*)(x + (size_t)tile0 * FIN);
    float4* lx = (float4*)xl;
    int nv = nrow * (FIN / 4);
    for (int i = tid; i < nv; i += 256) lx[i] = gx[i];
    __syncthreads();
    for (int r = wv; r < nrow; r += 4) {
        const float4* xr = (const float4*)(xl + r * FIN);
        float a0 = 0.f, a1 = 0.f, a2 = 0.f, a3 = 0.f;
        #pragma unroll
        for (int k4 = 0; k4 < FIN / 4; ++k4) {
            float4 v = xr[k4];
            a0 += v.x * Wreg[4 * k4 + 0];
            a1 += v.y * Wreg[4 * k4 + 1];
            a2 += v.z * Wreg[4 * k4 + 2];
            a3 += v.w * Wreg[4 * k4 + 3];
        }
        float sn = dinv2[tile0 + r];
        gbuf[(size_t)(tile0 + r) * HD + lane] = sn * ((a0 + a1) + (a2 + a3));
    }
}

// -- g2 = dinv2 * (relu(agg+b1) @ W2): W col in regs, relu fused into LDS stage --
__global__ __launch_bounds__(256) void k_mm2(const float* __restrict__ agg,
                                             const float* __restrict__ b1,
                                             const float* __restrict__ W2,
                                             const float* __restrict__ dinv2,
                                             float* __restrict__ gbuf, int N) {
    __shared__ float xl[128 * HD];  // 32 KiB
    int tid  = threadIdx.x;
    int lane = tid & 63;
    int wv   = tid >> 6;
    float Wreg[HD];
    #pragma unroll
    for (int k = 0; k < HD; ++k) Wreg[k] = W2[k * HD + lane];
    float4 bb = ((const float4*)b1)[tid & 15];
    int tile0 = blockIdx.x * 128;
    if (tile0 >= N) return;
    int nrow = min(128, N - tile0);
    const float4* gx = (const float4*)(agg + (size_t)tile0 * HD);
    float4* lx = (float4*)xl;
    int nv = nrow * (HD / 4);
    for (int i = tid; i < nv; i += 256) {
        float4 v = gx[i];
        v.x = fmaxf(v.x + bb.x, 0.f);
        v.y = fmaxf(v.y + bb.y, 0.f);
        v.z = fmaxf(v.z + bb.z, 0.f);
        v.w = fmaxf(v.w + bb.w, 0.f);
        lx[i] = v;
    }
    __syncthreads();
    for (int r = wv; r < nrow; r += 4) {
        const float4* xr = (const float4*)(xl + r * HD);
        float a0 = 0.f, a1 = 0.f, a2 = 0.f, a3 = 0.f;
        #pragma unroll
        for (int k4 = 0; k4 < HD / 4; ++k4) {
            float4 v = xr[k4];
            a0 += v.x * Wreg[4 * k4 + 0];
            a1 += v.y * Wreg[4 * k4 + 1];
            a2 += v.z * Wreg[4 * k4 + 2];
            a3 += v.w * Wreg[4 * k4 + 3];
        }
        float sn = dinv2[tile0 + r];
        gbuf[(size_t)(tile0 + r) * HD + lane] = sn * ((a0 + a1) + (a2 + a3));
    }
}

// ------- CSR gather: agg[c] = dinv2[c]*( g[c] + sum_e ew[e]*g[src[e]] ) -------
__global__ __launch_bounds__(256) void k_agg(const int* __restrict__ rowptr,
                                             const int* __restrict__ sidx,
                                             const float* __restrict__ sw,
                                             const float* __restrict__ g,
                                             const float* __restrict__ dinv2,
                                             float* __restrict__ agg, int N) {
    int lane = threadIdx.x & 63;
    int node = (blockIdx.x * 256 + threadIdx.x) >> 6;
    if (node >= N) return;
    int s = rowptr[node];
    int e = rowptr[node + 1];
    float a0 = g[(size_t)node * HD + lane];
    float a1 = 0.f, a2 = 0.f, a3 = 0.f;
    int p = s;
    for (; p + 4 <= e; p += 4) {
        int  s0 = sidx[p + 0], s1 = sidx[p + 1], s2 = sidx[p + 2], s3 = sidx[p + 3];
        float w0 = sw[p + 0], w1 = sw[p + 1], w2 = sw[p + 2], w3 = sw[p + 3];
        a0 += w0 * g[(size_t)s0 * HD + lane];
        a1 += w1 * g[(size_t)s1 * HD + lane];
        a2 += w2 * g[(size_t)s2 * HD + lane];
        a3 += w3 * g[(size_t)s3 * HD + lane];
    }
    for (; p < e; ++p)
        a0 += sw[p] * g[(size_t)sidx[p] * HD + lane];
    agg[(size_t)node * HD + lane] = dinv2[node] * ((a0 + a1) + (a2 + a3));
}

// ---------------- out = relu(agg + b2) @ Wout + bout ----------------
__global__ __launch_bounds__(256) void k_out(const float* __restrict__ agg,
                                             const float* __restrict__ b2,
                                             const float* __restrict__ Wout,
                                             const float* __restrict__ bout,
                                             float* __restrict__ out, int N) {
    __shared__ float Wl[HD * TD];
    __shared__ float bl[HD];
    __shared__ float bo[TD];
    for (int i = threadIdx.x; i < HD * TD; i += 256) Wl[i] = Wout[i];
    if (threadIdx.x < HD) bl[threadIdx.x] = b2[threadIdx.x];
    if (threadIdx.x < TD) bo[threadIdx.x] = bout[threadIdx.x];
    __syncthreads();
    int idx = blockIdx.x * 256 + threadIdx.x;
    if (idx >= N * TD) return;
    int n = idx / TD;
    int t = idx - n * TD;
    const float* a = agg + (size_t)n * HD;
    float acc = bo[t];
    #pragma unroll 8
    for (int k = 0; k < HD; ++k)
        acc += fmaxf(a[k] + bl[k], 0.f) * Wl[k * TD + t];
    out[idx] = acc;
}

extern "C" void kernel_launch(void* const* d_in, const int* in_sizes, int n_in,
                              void* d_out, int out_size, void* d_ws, size_t ws_size,
                              hipStream_t stream) {
    const float* x    = (const float*)d_in[0];
    const int*   ei   = (const int*)d_in[1];   // harness passes integers as int32
    const float* et   = (const float*)d_in[2];
    const float* W1   = (const float*)d_in[3];
    const float* b1   = (const float*)d_in[4];
    const float* W2   = (const float*)d_in[5];
    const float* b2   = (const float*)d_in[6];
    const float* Wout = (const float*)d_in[7];
    const float* bout = (const float*)d_in[8];
    float*       out  = (float*)d_out;

    int N = in_sizes[0] / FIN;
    int E = in_sizes[2];
    int NCHUNK = (N + CHUNK - 1) / CHUNK;          // 7 for N=100K
    int NB = (N + SCAN_ELEMS - 1) / SCAN_ELEMS;    // scan blocks (98)

    // --- workspace layout, 256B-aligned regions ---
    char*  base = (char*)d_ws;
    size_t ofs  = 0;
    auto alloc = [&](size_t bytes) -> char* {
        char* p = base + ofs;
        ofs = (ofs + bytes + 255) & ~(size_t)255;
        return p;
    };
    unsigned* tmaxb  = (unsigned*)alloc(64);
    float*    ebuf   = (float*)alloc((size_t)E * 4);        // decay
    float*    deg    = (float*)alloc((size_t)N * 4);        // deg -> dinv
    float*    deg2   = (float*)alloc((size_t)N * 4);        // deg2 -> dinv2
    int*      hist   = (int*)alloc((size_t)N * 4);
    int*      rowptr = (int*)alloc((size_t)(N + 1) * 4);
    int*      bsum   = (int*)alloc((size_t)1024 * 4);
    int*      boff   = (int*)alloc((size_t)1024 * 4);
    size_t privBytes = (size_t)NCHUNK * SPLIT * CHUNK * 4;  // 7.34 MB
    size_t csrBytes  = ((size_t)E * 4 + 255) & ~(size_t)255;
    // privD dead after k_deghist_red -> alias with sidx
    char*  privA = alloc(privBytes > csrBytes ? privBytes : csrBytes);
    float* privD = (float*)privA;
    int*   sidx  = (int*)privA;
    int*   privH = (int*)alloc(privBytes);                  // persists through k_fill
    float* sw    = (float*)alloc(csrBytes);
    float* gbuf  = (float*)alloc((size_t)N * HD * 4);
    float* agg   = (float*)alloc((size_t)N * HD * 4);

    int bN  = (N + 255) / 256;
    int bT1 = (N + 63) / 64;
    int bT2 = (N + 127) / 128;
    int bWN = (N * HD + 255) / 256;

    k_init       <<<1,   64,  0, stream>>>(tmaxb);
    k_tmax       <<<256, 256, 0, stream>>>(et, tmaxb, E);
    k_deghist    <<<NCHUNK * SPLIT, 1024, 0, stream>>>(ei, et, tmaxb, ebuf, privD, privH, E, N);
    k_deghist_red<<<bN,  256, 0, stream>>>(privD, privH, deg, hist, N);
    k_rsqrt      <<<bN,  256, 0, stream>>>(deg, N);
    k_scan_a     <<<NB,  256, 0, stream>>>(hist, bsum, N);
    k_scan_b     <<<1,  1024, 0, stream>>>(bsum, boff, NB, rowptr + N);
    k_scan_c     <<<NB,  256, 0, stream>>>(hist, boff, rowptr, N);
    k_fill       <<<NCHUNK * SPLIT, 1024, 0, stream>>>(ei, ebuf, deg, rowptr, privH, sidx, sw, E, N);
    k_deg2       <<<bN,  256, 0, stream>>>(rowptr, sw, deg2, N);
    k_rsqrt      <<<bN,  256, 0, stream>>>(deg2, N);

    k_mm1        <<<bT1, 256, 0, stream>>>(x, W1, deg2, gbuf, N);
    k_agg        <<<bWN, 256, 0, stream>>>(rowptr, sidx, sw, gbuf, deg2, agg, N);
    k_mm2        <<<bT2, 256, 0, stream>>>(agg, b1, W2, deg2, gbuf, N);
    k_agg        <<<bWN, 256, 0, stream>>>(rowptr, sidx, sw, gbuf, deg2, agg, N);
    k_out        <<<(N * TD + 255) / 256, 256, 0, stream>>>(agg, b2, Wout, bout, out, N);
}

// Round 9
// 368.766 us; speedup vs baseline: 6.3494x; 1.2956x over previous
//
#include <hip/hip_runtime.h>

#define ALPHA 0.1f
#define FIN 128
#define HD 64
#define TD 10
#define SCAN_ELEMS 1024
#define CHUNK 16384           // nodes per LDS chunk (2^14)
#define SPLIT 16              // edge-slices per chunk

typedef __attribute__((ext_vector_type(8))) short short8v;   // 8 bf16 (4 VGPRs)
typedef __attribute__((ext_vector_type(4))) float f32x4;

__device__ __forceinline__ unsigned short f2bf(float f) {    // RNE f32->bf16
    unsigned u = __float_as_uint(f);
    return (unsigned short)((u + 0x7FFFu + ((u >> 16) & 1u)) >> 16);
}
__device__ __forceinline__ unsigned pack2(float a, float b) {
    return (unsigned)f2bf(a) | ((unsigned)f2bf(b) << 16);
}

// ---------------- init: tmax=0 ----------------
__global__ __launch_bounds__(64) void k_init(unsigned* tmaxb) {
    if (threadIdx.x == 0) *tmaxb = 0u;
}

// ------- convert W1 (128x64 f32) -> W1t bf16 [64][128]; W2 (64x64) -> W2t [64][64] -------
__global__ __launch_bounds__(256) void k_cvtW(const float* __restrict__ W1,
                                              const float* __restrict__ W2,
                                              unsigned short* __restrict__ W1t,
                                              unsigned short* __restrict__ W2t) {
    int t = blockIdx.x * 256 + threadIdx.x;
    if (t < FIN * HD) {                       // 8192
        int c = t >> 7, k = t & 127;
        W1t[t] = f2bf(W1[k * HD + c]);
    }
    if (t < HD * HD) {                        // 4096
        int c = t >> 6, k = t & 63;
        W2t[t] = f2bf(W2[k * HD + c]);
    }
}

// ---------------- max(edge_time): block-reduced, 1 atomic per block ----------------
__global__ __launch_bounds__(256) void k_tmax(const float* __restrict__ t, unsigned* tmaxb, int E) {
    __shared__ unsigned sm[4];
    unsigned m = 0u;
    for (int i = blockIdx.x * 256 + threadIdx.x; i < E; i += gridDim.x * 256)
        m = max(m, __float_as_uint(t[i]));
    #pragma unroll
    for (int off = 32; off > 0; off >>= 1)
        m = max(m, (unsigned)__shfl_down((int)m, off, 64));
    if ((threadIdx.x & 63) == 0) sm[threadIdx.x >> 6] = m;
    __syncthreads();
    if (threadIdx.x == 0) {
        m = max(max(sm[0], sm[1]), max(sm[2], sm[3]));
        atomicMax(tmaxb, m);
    }
}

// ------ chunked LDS-privatized deg(row,decay-weighted) + hist(col) ------
__global__ __launch_bounds__(1024) void k_deghist(const int* __restrict__ ei,
                                                  const float* __restrict__ t,
                                                  const unsigned* __restrict__ tmaxb,
                                                  float* __restrict__ ebuf,
                                                  float* __restrict__ privD,
                                                  int* __restrict__ privH,
                                                  int E, int N) {
    __shared__ float ldsD[CHUNK];   // 64 KiB
    __shared__ int   ldsH[CHUNK];   // 64 KiB
    int c = blockIdx.x / SPLIT;
    int b = blockIdx.x - c * SPLIT;
    int base = c * CHUNK;
    for (int i = threadIdx.x; i < CHUNK; i += 1024) { ldsD[i] = 0.f; ldsH[i] = 0; }
    __syncthreads();
    float tmax = __uint_as_float(*tmaxb);
    long long e0 = (long long)E * b / SPLIT;
    long long e1 = (long long)E * (b + 1) / SPLIT;
    for (long long e = e0 + threadIdx.x; e < e1; e += 1024) {
        int r  = ei[e];
        int cc = ei[E + e];
        float d = expf(-ALPHA * (tmax - t[e]));
        if (c == 0) ebuf[e] = d;
        unsigned rr = (unsigned)(r - base);
        if (rr < CHUNK) atomicAdd(&ldsD[rr], d);
        unsigned cr = (unsigned)(cc - base);
        if (cr < CHUNK) atomicAdd(&ldsH[cr], 1);
    }
    __syncthreads();
    float* pd = privD + ((size_t)c * SPLIT + b) * CHUNK;
    int*   ph = privH + ((size_t)c * SPLIT + b) * CHUNK;
    for (int i = threadIdx.x; i < CHUNK; i += 1024) { pd[i] = ldsD[i]; ph[i] = ldsH[i]; }
}

// ------ reduce SPLIT private copies -> deg, hist; privH -> per-slice EXCLUSIVE prefix ------
__global__ __launch_bounds__(256) void k_deghist_red(const float* __restrict__ privD,
                                                     int* __restrict__ privH,
                                                     float* __restrict__ deg,
                                                     int* __restrict__ hist, int N) {
    int n = blockIdx.x * 256 + threadIdx.x;
    if (n >= N) return;
    int c = n >> 14;              // /CHUNK
    int i = n & (CHUNK - 1);
    const float* pd = privD + ((size_t)c * SPLIT) * CHUNK + i;
    int*         ph = privH + ((size_t)c * SPLIT) * CHUNK + i;
    float s = 0.f; int run = 0;
    #pragma unroll
    for (int b = 0; b < SPLIT; ++b) {
        s += pd[(size_t)b * CHUNK];
        int t = ph[(size_t)b * CHUNK];
        ph[(size_t)b * CHUNK] = run;       // exclusive prefix within node bucket
        run += t;
    }
    deg[n] = s;
    hist[n] = run;
}

// ---------------- in-place a = a>0 ? rsqrt(a) : 0 ----------------
__global__ __launch_bounds__(256) void k_rsqrt(float* a, int N) {
    int i = blockIdx.x * 256 + threadIdx.x;
    if (i >= N) return;
    float v = a[i];
    a[i] = v > 0.f ? rsqrtf(v) : 0.f;
}

// ---------------- scan phase A: per-block sum of 1024-elem hist chunk ----------------
__global__ __launch_bounds__(256) void k_scan_a(const int* __restrict__ hist,
                                                int* __restrict__ bsum, int N) {
    __shared__ int sm[4];
    int base = blockIdx.x * SCAN_ELEMS + threadIdx.x * 4;
    int s = 0;
    if (base + 3 < N) {
        int4 v = *(const int4*)(hist + base);
        s = v.x + v.y + v.z + v.w;
    } else {
        for (int i = base; i < N && i < base + 4; ++i) s += hist[i];
    }
    #pragma unroll
    for (int off = 32; off > 0; off >>= 1) s += __shfl_down(s, off, 64);
    if ((threadIdx.x & 63) == 0) sm[threadIdx.x >> 6] = s;
    __syncthreads();
    if (threadIdx.x == 0) bsum[blockIdx.x] = sm[0] + sm[1] + sm[2] + sm[3];
}

// ------- scan phase B: 1 block scans <=1024 partials; writes rowptr[N]=total -------
__global__ __launch_bounds__(1024) void k_scan_b(const int* __restrict__ bsum,
                                                 int* __restrict__ boff,
                                                 int NB, int* __restrict__ rowptrN) {
    __shared__ int part[1024];
    int tid = threadIdx.x;
    int v = (tid < NB) ? bsum[tid] : 0;
    part[tid] = v;
    __syncthreads();
    for (int d = 1; d < 1024; d <<= 1) {
        int t = (tid >= d) ? part[tid - d] : 0;
        __syncthreads();
        part[tid] += t;
        __syncthreads();
    }
    if (tid < NB) boff[tid] = part[tid] - v;
    if (tid == 1023) *rowptrN = part[1023];
}

// ------- scan phase C: block-local scan + block offset -> rowptr ----------
__global__ __launch_bounds__(256) void k_scan_c(const int* __restrict__ hist,
                                                const int* __restrict__ boff,
                                                int* __restrict__ rowptr, int N) {
    __shared__ int part[256];
    int base = blockIdx.x * SCAN_ELEMS + threadIdx.x * 4;
    int vv[4] = {0, 0, 0, 0};
    if (base + 3 < N) {
        int4 v = *(const int4*)(hist + base);
        vv[0] = v.x; vv[1] = v.y; vv[2] = v.z; vv[3] = v.w;
    } else {
        for (int i = 0; i < 4; ++i) if (base + i < N) vv[i] = hist[base + i];
    }
    int s = vv[0] + vv[1] + vv[2] + vv[3];
    part[threadIdx.x] = s;
    __syncthreads();
    for (int d = 1; d < 256; d <<= 1) {
        int t = (threadIdx.x >= d) ? part[threadIdx.x - d] : 0;
        __syncthreads();
        part[threadIdx.x] += t;
        __syncthreads();
    }
    int run = boff[blockIdx.x] + part[threadIdx.x] - s;
    int pp[4];
    pp[0] = run;
    pp[1] = pp[0] + vv[0];
    pp[2] = pp[1] + vv[1];
    pp[3] = pp[2] + vv[2];
    if (base + 3 < N) {
        *(int4*)(rowptr + base) = make_int4(pp[0], pp[1], pp[2], pp[3]);
    } else {
        for (int i = 0; i < 4; ++i)
            if (base + i < N) rowptr[base + i] = pp[i];
    }
}

// ------- chunked CSR fill, NO device atomics: LDS cursor owned per (chunk,slice) -------
__global__ __launch_bounds__(1024) void k_fill(const int* __restrict__ ei,
                                               const float* __restrict__ ebuf,
                                               const float* __restrict__ dinv,
                                               const int* __restrict__ rowptr,
                                               const int* __restrict__ privH,
                                               int* __restrict__ sidx,
                                               float* __restrict__ sw,
                                               int E, int N) {
    __shared__ int cur[CHUNK];      // 64 KiB
    int c = blockIdx.x / SPLIT;
    int b = blockIdx.x - c * SPLIT;
    int base = c * CHUNK;
    int lim = min(CHUNK, N - base);
    const int* ph = privH + ((size_t)c * SPLIT + b) * CHUNK;
    for (int i = threadIdx.x; i < lim; i += 1024)
        cur[i] = rowptr[base + i] + ph[i];
    __syncthreads();
    long long e0 = (long long)E * b / SPLIT;
    long long e1 = (long long)E * (b + 1) / SPLIT;
    for (long long e = e0 + threadIdx.x; e < e1; e += 1024) {
        int cc = ei[E + e];
        unsigned cr = (unsigned)(cc - base);
        if (cr < (unsigned)lim) {
            int r = ei[e];
            int pos = atomicAdd(&cur[cr], 1);   // LDS atomic, block-exclusive
            sidx[pos] = r;
            sw[pos]   = dinv[r] * ebuf[e] * dinv[cc];
        }
    }
}

// ------- deg2[c] = 1 + segment_sum(sw over bucket c)  (no atomics) -------
__global__ __launch_bounds__(256) void k_deg2(const int* __restrict__ rowptr,
                                              const float* __restrict__ sw,
                                              float* __restrict__ deg2, int N) {
    int n = blockIdx.x * 256 + threadIdx.x;
    if (n >= N) return;
    int s = rowptr[n], e = rowptr[n + 1];
    float a = 1.f;
    for (int p = s; p < e; ++p) a += sw[p];
    deg2[n] = a;
}

// ======== g1 = dinv2 * (x @ W1) via MFMA 16x16x32 bf16 ========
// 64-row tile/block; wave w owns rows 16w..16w+15; B (W1t) frags from global (L2).
// LDS x-tile bf16 [64][128], XOR-swizzled: byte ^= (row&7)<<4.
__global__ __launch_bounds__(256) void k_mm1(const float* __restrict__ x,
                                             const unsigned short* __restrict__ W1t,
                                             const float* __restrict__ dinv2,
                                             float* __restrict__ gbuf, int N) {
    __shared__ __align__(16) unsigned short xb[64 * FIN];   // 16 KiB
    int tid  = threadIdx.x;
    int lane = tid & 63;
    int w    = tid >> 6;
    int lrow = lane & 15;
    int lk8  = lane >> 4;          // 0..3
    int tile0 = blockIdx.x * 64;
    if (tile0 >= N) return;
    int nrow = min(64, N - tile0);

    // B fragments: breg[kk][ct], lane holds col=16ct+lrow, k=kk*32+lk8*8..+7
    short8v breg[4][4];
    #pragma unroll
    for (int kk = 0; kk < 4; ++kk)
        #pragma unroll
        for (int ct = 0; ct < 4; ++ct)
            breg[kk][ct] = *(const short8v*)(W1t + (16 * ct + lrow) * FIN + kk * 32 + lk8 * 8);

    // stage x tile -> bf16 LDS (RNE), swizzled
    const float4* gx = (const float4*)(x + (size_t)tile0 * FIN);
    int nv = nrow * (FIN / 4);
    for (int i = tid; i < nv; i += 256) {
        float4 v = gx[i];
        int row = i >> 5;                      // FIN/4 = 32 float4 per row
        int byte = row * 256 + (i & 31) * 8;
        unsigned swz = (unsigned)(byte ^ ((row & 7) << 4));
        uint2 p = make_uint2(pack2(v.x, v.y), pack2(v.z, v.w));
        *(uint2*)((char*)xb + swz) = p;
    }
    __syncthreads();

    f32x4 acc[4];
    #pragma unroll
    for (int ct = 0; ct < 4; ++ct) acc[ct] = 0.f;
    int arow = 16 * w + lrow;
    #pragma unroll
    for (int kk = 0; kk < 4; ++kk) {
        int byte = arow * 256 + kk * 64 + lk8 * 16;
        unsigned swz = (unsigned)(byte ^ ((arow & 7) << 4));
        short8v a = *(const short8v*)((const char*)xb + swz);
        #pragma unroll
        for (int ct = 0; ct < 4; ++ct)
            acc[ct] = __builtin_amdgcn_mfma_f32_16x16x32_bf16(a, breg[kk][ct], acc[ct], 0, 0, 0);
    }
    // D: row = 16w + lk8*4 + i, col = 16ct + lrow
    #pragma unroll
    for (int i = 0; i < 4; ++i) {
        int grow = tile0 + 16 * w + lk8 * 4 + i;
        if (grow < N) {
            float sn = dinv2[grow];
            #pragma unroll
            for (int ct = 0; ct < 4; ++ct)
                gbuf[(size_t)grow * HD + 16 * ct + lrow] = sn * acc[ct][i];
        }
    }
}

// ======== g2 = dinv2 * (relu(agg+b1) @ W2) via MFMA, K=64 ========
__global__ __launch_bounds__(256) void k_mm2(const float* __restrict__ agg,
                                             const float* __restrict__ b1,
                                             const unsigned short* __restrict__ W2t,
                                             const float* __restrict__ dinv2,
                                             float* __restrict__ gbuf, int N) {
    __shared__ __align__(16) unsigned short xb[64 * HD];    // 8 KiB
    int tid  = threadIdx.x;
    int lane = tid & 63;
    int w    = tid >> 6;
    int lrow = lane & 15;
    int lk8  = lane >> 4;
    int tile0 = blockIdx.x * 64;
    if (tile0 >= N) return;
    int nrow = min(64, N - tile0);

    short8v breg[2][4];
    #pragma unroll
    for (int kk = 0; kk < 2; ++kk)
        #pragma unroll
        for (int ct = 0; ct < 4; ++ct)
            breg[kk][ct] = *(const short8v*)(W2t + (16 * ct + lrow) * HD + kk * 32 + lk8 * 8);

    const float4* gx = (const float4*)(agg + (size_t)tile0 * HD);
    const float4* bf4 = (const float4*)b1;
    int nv = nrow * (HD / 4);
    for (int i = tid; i < nv; i += 256) {
        float4 v = gx[i];
        float4 bb = bf4[i & 15];
        v.x = fmaxf(v.x + bb.x, 0.f);
        v.y = fmaxf(v.y + bb.y, 0.f);
        v.z = fmaxf(v.z + bb.z, 0.f);
        v.w = fmaxf(v.w + bb.w, 0.f);
        int row = i >> 4;                      // HD/4 = 16 float4 per row
        int byte = row * 128 + (i & 15) * 8;
        unsigned swz = (unsigned)(byte ^ ((row & 7) << 4));
        *(uint2*)((char*)xb + swz) = make_uint2(pack2(v.x, v.y), pack2(v.z, v.w));
    }
    __syncthreads();

    f32x4 acc[4];
    #pragma unroll
    for (int ct = 0; ct < 4; ++ct) acc[ct] = 0.f;
    int arow = 16 * w + lrow;
    #pragma unroll
    for (int kk = 0; kk < 2; ++kk) {
        int byte = arow * 128 + kk * 64 + lk8 * 16;
        unsigned swz = (unsigned)(byte ^ ((arow & 7) << 4));
        short8v a = *(const short8v*)((const char*)xb + swz);
        #pragma unroll
        for (int ct = 0; ct < 4; ++ct)
            acc[ct] = __builtin_amdgcn_mfma_f32_16x16x32_bf16(a, breg[kk][ct], acc[ct], 0, 0, 0);
    }
    #pragma unroll
    for (int i = 0; i < 4; ++i) {
        int grow = tile0 + 16 * w + lk8 * 4 + i;
        if (grow < N) {
            float sn = dinv2[grow];
            #pragma unroll
            for (int ct = 0; ct < 4; ++ct)
                gbuf[(size_t)grow * HD + 16 * ct + lrow] = sn * acc[ct][i];
        }
    }
}

// ------- CSR gather: agg[c] = dinv2[c]*( g[c] + sum_e ew[e]*g[src[e]] ) -------
__global__ __launch_bounds__(256) void k_agg(const int* __restrict__ rowptr,
                                             const int* __restrict__ sidx,
                                             const float* __restrict__ sw,
                                             const float* __restrict__ g,
                                             const float* __restrict__ dinv2,
                                             float* __restrict__ agg, int N) {
    int lane = threadIdx.x & 63;
    int node = (blockIdx.x * 256 + threadIdx.x) >> 6;
    if (node >= N) return;
    int s = rowptr[node];
    int e = rowptr[node + 1];
    float a0 = g[(size_t)node * HD + lane];
    float a1 = 0.f, a2 = 0.f, a3 = 0.f;
    int p = s;
    for (; p + 4 <= e; p += 4) {
        int  s0 = sidx[p + 0], s1 = sidx[p + 1], s2 = sidx[p + 2], s3 = sidx[p + 3];
        float w0 = sw[p + 0], w1 = sw[p + 1], w2 = sw[p + 2], w3 = sw[p + 3];
        a0 += w0 * g[(size_t)s0 * HD + lane];
        a1 += w1 * g[(size_t)s1 * HD + lane];
        a2 += w2 * g[(size_t)s2 * HD + lane];
        a3 += w3 * g[(size_t)s3 * HD + lane];
    }
    for (; p < e; ++p)
        a0 += sw[p] * g[(size_t)sidx[p] * HD + lane];
    agg[(size_t)node * HD + lane] = dinv2[node] * ((a0 + a1) + (a2 + a3));
}

// ---------------- out = relu(agg + b2) @ Wout + bout ----------------
__global__ __launch_bounds__(256) void k_out(const float* __restrict__ agg,
                                             const float* __restrict__ b2,
                                             const float* __restrict__ Wout,
                                             const float* __restrict__ bout,
                                             float* __restrict__ out, int N) {
    __shared__ float Wl[HD * TD];
    __shared__ float bl[HD];
    __shared__ float bo[TD];
    for (int i = threadIdx.x; i < HD * TD; i += 256) Wl[i] = Wout[i];
    if (threadIdx.x < HD) bl[threadIdx.x] = b2[threadIdx.x];
    if (threadIdx.x < TD) bo[threadIdx.x] = bout[threadIdx.x];
    __syncthreads();
    int idx = blockIdx.x * 256 + threadIdx.x;
    if (idx >= N * TD) return;
    int n = idx / TD;
    int t = idx - n * TD;
    const float* a = agg + (size_t)n * HD;
    float acc = bo[t];
    #pragma unroll 8
    for (int k = 0; k < HD; ++k)
        acc += fmaxf(a[k] + bl[k], 0.f) * Wl[k * TD + t];
    out[idx] = acc;
}

extern "C" void kernel_launch(void* const* d_in, const int* in_sizes, int n_in,
                              void* d_out, int out_size, void* d_ws, size_t ws_size,
                              hipStream_t stream) {
    const float* x    = (const float*)d_in[0];
    const int*   ei   = (const int*)d_in[1];   // harness passes integers as int32
    const float* et   = (const float*)d_in[2];
    const float* W1   = (const float*)d_in[3];
    const float* b1   = (const float*)d_in[4];
    const float* W2   = (const float*)d_in[5];
    const float* b2   = (const float*)d_in[6];
    const float* Wout = (const float*)d_in[7];
    const float* bout = (const float*)d_in[8];
    float*       out  = (float*)d_out;

    int N = in_sizes[0] / FIN;
    int E = in_sizes[2];
    int NCHUNK = (N + CHUNK - 1) / CHUNK;          // 7 for N=100K
    int NB = (N + SCAN_ELEMS - 1) / SCAN_ELEMS;    // scan blocks (98)

    // --- workspace layout, 256B-aligned regions ---
    char*  base = (char*)d_ws;
    size_t ofs  = 0;
    auto alloc = [&](size_t bytes) -> char* {
        char* p = base + ofs;
        ofs = (ofs + bytes + 255) & ~(size_t)255;
        return p;
    };
    unsigned*       tmaxb = (unsigned*)alloc(64);
    unsigned short* W1t   = (unsigned short*)alloc((size_t)FIN * HD * 2);
    unsigned short* W2t   = (unsigned short*)alloc((size_t)HD * HD * 2);
    float*    ebuf   = (float*)alloc((size_t)E * 4);        // decay
    float*    deg    = (float*)alloc((size_t)N * 4);        // deg -> dinv
    float*    deg2   = (float*)alloc((size_t)N * 4);        // deg2 -> dinv2
    int*      hist   = (int*)alloc((size_t)N * 4);
    int*      rowptr = (int*)alloc((size_t)(N + 1) * 4);
    int*      bsum   = (int*)alloc((size_t)1024 * 4);
    int*      boff   = (int*)alloc((size_t)1024 * 4);
    size_t privBytes = (size_t)NCHUNK * SPLIT * CHUNK * 4;  // 7.34 MB
    size_t csrBytes  = ((size_t)E * 4 + 255) & ~(size_t)255;
    // privD dead after k_deghist_red -> alias with sidx
    char*  privA = alloc(privBytes > csrBytes ? privBytes : csrBytes);
    float* privD = (float*)privA;
    int*   sidx  = (int*)privA;
    int*   privH = (int*)alloc(privBytes);                  // persists through k_fill
    float* sw    = (float*)alloc(csrBytes);
    float* gbuf  = (float*)alloc((size_t)N * HD * 4);
    float* agg   = (float*)alloc((size_t)N * HD * 4);

    int bN  = (N + 255) / 256;
    int bT  = (N + 63) / 64;
    int bWN = (N * HD + 255) / 256;

    k_init       <<<1,   64,  0, stream>>>(tmaxb);
    k_cvtW       <<<32,  256, 0, stream>>>(W1, W2, W1t, W2t);
    k_tmax       <<<256, 256, 0, stream>>>(et, tmaxb, E);
    k_deghist    <<<NCHUNK * SPLIT, 1024, 0, stream>>>(ei, et, tmaxb, ebuf, privD, privH, E, N);
    k_deghist_red<<<bN,  256, 0, stream>>>(privD, privH, deg, hist, N);
    k_rsqrt      <<<bN,  256, 0, stream>>>(deg, N);
    k_scan_a     <<<NB,  256, 0, stream>>>(hist, bsum, N);
    k_scan_b     <<<1,  1024, 0, stream>>>(bsum, boff, NB, rowptr + N);
    k_scan_c     <<<NB,  256, 0, stream>>>(hist, boff, rowptr, N);
    k_fill       <<<NCHUNK * SPLIT, 1024, 0, stream>>>(ei, ebuf, deg, rowptr, privH, sidx, sw, E, N);
    k_deg2       <<<bN,  256, 0, stream>>>(rowptr, sw, deg2, N);
    k_rsqrt      <<<bN,  256, 0, stream>>>(deg2, N);

    k_mm1        <<<bT,  256, 0, stream>>>(x, W1t, deg2, gbuf, N);
    k_agg        <<<bWN, 256, 0, stream>>>(rowptr, sidx, sw, gbuf, deg2, agg, N);
    k_mm2        <<<bT,  256, 0, stream>>>(agg, b1, W2t, deg2, gbuf, N);
    k_agg        <<<bWN, 256, 0, stream>>>(rowptr, sidx, sw, gbuf, deg2, agg, N);
    k_out        <<<(N * TD + 255) / 256, 256, 0, stream>>>(agg, b2, Wout, bout, out, N);
}

// Round 10
// 343.720 us; speedup vs baseline: 6.8121x; 1.0729x over previous
//
#include <hip/hip_runtime.h>

#define ALPHA 0.1f
#define FIN 128
#define HD 64
#define TD 10
#define SCAN_ELEMS 1024
#define CHUNK 16384           // nodes per LDS chunk (2^14)
#define SPLIT 16              // edge-slices per chunk

typedef __attribute__((ext_vector_type(8))) short short8v;   // 8 bf16 (4 VGPRs)
typedef __attribute__((ext_vector_type(4))) float f32x4;

__device__ __forceinline__ unsigned short f2bf(float f) {    // RNE f32->bf16
    unsigned u = __float_as_uint(f);
    return (unsigned short)((u + 0x7FFFu + ((u >> 16) & 1u)) >> 16);
}
__device__ __forceinline__ unsigned pack2(float a, float b) {
    return (unsigned)f2bf(a) | ((unsigned)f2bf(b) << 16);
}
__device__ __forceinline__ float bf2f(unsigned short u) {
    return __uint_as_float((unsigned)u << 16);
}

// ------- convert W1/W2 -> transposed bf16 tables; also init tmax -------
__global__ __launch_bounds__(256) void k_cvtW(const float* __restrict__ W1,
                                              const float* __restrict__ W2,
                                              unsigned short* __restrict__ W1t,
                                              unsigned short* __restrict__ W2t,
                                              unsigned* tmaxb) {
    int t = blockIdx.x * 256 + threadIdx.x;
    if (t == 0) *tmaxb = 0u;
    if (t < FIN * HD) {                       // 8192
        int c = t >> 7, k = t & 127;
        W1t[t] = f2bf(W1[k * HD + c]);
    }
    if (t < HD * HD) {                        // 4096
        int c = t >> 6, k = t & 63;
        W2t[t] = f2bf(W2[k * HD + c]);
    }
}

// ---------------- max(edge_time): block-reduced, 1 atomic per block ----------------
__global__ __launch_bounds__(256) void k_tmax(const float* __restrict__ t, unsigned* tmaxb, int E) {
    __shared__ unsigned sm[4];
    unsigned m = 0u;
    for (int i = blockIdx.x * 256 + threadIdx.x; i < E; i += gridDim.x * 256)
        m = max(m, __float_as_uint(t[i]));
    #pragma unroll
    for (int off = 32; off > 0; off >>= 1)
        m = max(m, (unsigned)__shfl_down((int)m, off, 64));
    if ((threadIdx.x & 63) == 0) sm[threadIdx.x >> 6] = m;
    __syncthreads();
    if (threadIdx.x == 0) {
        m = max(max(sm[0], sm[1]), max(sm[2], sm[3]));
        atomicMax(tmaxb, m);
    }
}

// ------ chunked LDS-privatized deg(row,decay-weighted) + hist(col) ------
__global__ __launch_bounds__(1024) void k_deghist(const int* __restrict__ ei,
                                                  const float* __restrict__ t,
                                                  const unsigned* __restrict__ tmaxb,
                                                  float* __restrict__ ebuf,
                                                  float* __restrict__ privD,
                                                  int* __restrict__ privH,
                                                  int E, int N) {
    __shared__ float ldsD[CHUNK];   // 64 KiB
    __shared__ int   ldsH[CHUNK];   // 64 KiB
    int c = blockIdx.x / SPLIT;
    int b = blockIdx.x - c * SPLIT;
    int base = c * CHUNK;
    for (int i = threadIdx.x; i < CHUNK; i += 1024) { ldsD[i] = 0.f; ldsH[i] = 0; }
    __syncthreads();
    float tmax = __uint_as_float(*tmaxb);
    long long e0 = (long long)E * b / SPLIT;
    long long e1 = (long long)E * (b + 1) / SPLIT;
    for (long long e = e0 + threadIdx.x; e < e1; e += 1024) {
        int r  = ei[e];
        int cc = ei[E + e];
        float d = expf(-ALPHA * (tmax - t[e]));
        if (c == 0) ebuf[e] = d;
        unsigned rr = (unsigned)(r - base);
        if (rr < CHUNK) atomicAdd(&ldsD[rr], d);
        unsigned cr = (unsigned)(cc - base);
        if (cr < CHUNK) atomicAdd(&ldsH[cr], 1);
    }
    __syncthreads();
    float* pd = privD + ((size_t)c * SPLIT + b) * CHUNK;
    int*   ph = privH + ((size_t)c * SPLIT + b) * CHUNK;
    for (int i = threadIdx.x; i < CHUNK; i += 1024) { pd[i] = ldsD[i]; ph[i] = ldsH[i]; }
}

// ------ reduce SPLIT copies -> dinv (=rsqrt(deg)), hist; privH -> per-slice EXCL prefix ------
__global__ __launch_bounds__(256) void k_deghist_red(const float* __restrict__ privD,
                                                     int* __restrict__ privH,
                                                     float* __restrict__ dinv,
                                                     int* __restrict__ hist, int N) {
    int n = blockIdx.x * 256 + threadIdx.x;
    if (n >= N) return;
    int c = n >> 14;              // /CHUNK
    int i = n & (CHUNK - 1);
    const float* pd = privD + ((size_t)c * SPLIT) * CHUNK + i;
    int*         ph = privH + ((size_t)c * SPLIT) * CHUNK + i;
    float s = 0.f; int run = 0;
    #pragma unroll
    for (int b = 0; b < SPLIT; ++b) {
        s += pd[(size_t)b * CHUNK];
        int t = ph[(size_t)b * CHUNK];
        ph[(size_t)b * CHUNK] = run;       // exclusive prefix within node bucket
        run += t;
    }
    dinv[n] = s > 0.f ? rsqrtf(s) : 0.f;
    hist[n] = run;
}

// ---------------- scan phase A: per-block sum of 1024-elem hist chunk ----------------
__global__ __launch_bounds__(256) void k_scan_a(const int* __restrict__ hist,
                                                int* __restrict__ bsum, int N) {
    __shared__ int sm[4];
    int base = blockIdx.x * SCAN_ELEMS + threadIdx.x * 4;
    int s = 0;
    if (base + 3 < N) {
        int4 v = *(const int4*)(hist + base);
        s = v.x + v.y + v.z + v.w;
    } else {
        for (int i = base; i < N && i < base + 4; ++i) s += hist[i];
    }
    #pragma unroll
    for (int off = 32; off > 0; off >>= 1) s += __shfl_down(s, off, 64);
    if ((threadIdx.x & 63) == 0) sm[threadIdx.x >> 6] = s;
    __syncthreads();
    if (threadIdx.x == 0) bsum[blockIdx.x] = sm[0] + sm[1] + sm[2] + sm[3];
}

// ------- scan phase B: 1 block scans <=1024 partials; writes rowptr[N]=total -------
__global__ __launch_bounds__(1024) void k_scan_b(const int* __restrict__ bsum,
                                                 int* __restrict__ boff,
                                                 int NB, int* __restrict__ rowptrN) {
    __shared__ int part[1024];
    int tid = threadIdx.x;
    int v = (tid < NB) ? bsum[tid] : 0;
    part[tid] = v;
    __syncthreads();
    for (int d = 1; d < 1024; d <<= 1) {
        int t = (tid >= d) ? part[tid - d] : 0;
        __syncthreads();
        part[tid] += t;
        __syncthreads();
    }
    if (tid < NB) boff[tid] = part[tid] - v;
    if (tid == 1023) *rowptrN = part[1023];
}

// ------- scan phase C: block-local scan + block offset -> rowptr ----------
__global__ __launch_bounds__(256) void k_scan_c(const int* __restrict__ hist,
                                                const int* __restrict__ boff,
                                                int* __restrict__ rowptr, int N) {
    __shared__ int part[256];
    int base = blockIdx.x * SCAN_ELEMS + threadIdx.x * 4;
    int vv[4] = {0, 0, 0, 0};
    if (base + 3 < N) {
        int4 v = *(const int4*)(hist + base);
        vv[0] = v.x; vv[1] = v.y; vv[2] = v.z; vv[3] = v.w;
    } else {
        for (int i = 0; i < 4; ++i) if (base + i < N) vv[i] = hist[base + i];
    }
    int s = vv[0] + vv[1] + vv[2] + vv[3];
    part[threadIdx.x] = s;
    __syncthreads();
    for (int d = 1; d < 256; d <<= 1) {
        int t = (threadIdx.x >= d) ? part[threadIdx.x - d] : 0;
        __syncthreads();
        part[threadIdx.x] += t;
        __syncthreads();
    }
    int run = boff[blockIdx.x] + part[threadIdx.x] - s;
    int pp[4];
    pp[0] = run;
    pp[1] = pp[0] + vv[0];
    pp[2] = pp[1] + vv[1];
    pp[3] = pp[2] + vv[2];
    if (base + 3 < N) {
        *(int4*)(rowptr + base) = make_int4(pp[0], pp[1], pp[2], pp[3]);
    } else {
        for (int i = 0; i < 4; ++i)
            if (base + i < N) rowptr[base + i] = pp[i];
    }
}

// ------- chunked CSR fill: packed int2 (src, w-bits), LDS cursor, no device atomics -------
__global__ __launch_bounds__(1024) void k_fill(const int* __restrict__ ei,
                                               const float* __restrict__ ebuf,
                                               const float* __restrict__ dinv,
                                               const int* __restrict__ rowptr,
                                               const int* __restrict__ privH,
                                               int2* __restrict__ pairs,
                                               int E, int N) {
    __shared__ int cur[CHUNK];      // 64 KiB
    int c = blockIdx.x / SPLIT;
    int b = blockIdx.x - c * SPLIT;
    int base = c * CHUNK;
    int lim = min(CHUNK, N - base);
    const int* ph = privH + ((size_t)c * SPLIT + b) * CHUNK;
    for (int i = threadIdx.x; i < lim; i += 1024)
        cur[i] = rowptr[base + i] + ph[i];
    __syncthreads();
    long long e0 = (long long)E * b / SPLIT;
    long long e1 = (long long)E * (b + 1) / SPLIT;
    for (long long e = e0 + threadIdx.x; e < e1; e += 1024) {
        int cc = ei[E + e];
        unsigned cr = (unsigned)(cc - base);
        if (cr < (unsigned)lim) {
            int r = ei[e];
            int pos = atomicAdd(&cur[cr], 1);   // LDS atomic, block-exclusive
            float w = dinv[r] * ebuf[e] * dinv[cc];
            pairs[pos] = make_int2(r, __float_as_int(w));
        }
    }
}

// ------- dinv2[c] = rsqrt(1 + segment_sum(w))  (no atomics) -------
__global__ __launch_bounds__(256) void k_deg2(const int* __restrict__ rowptr,
                                              const int2* __restrict__ pairs,
                                              float* __restrict__ dinv2, int N) {
    int n = blockIdx.x * 256 + threadIdx.x;
    if (n >= N) return;
    int s = rowptr[n], e = rowptr[n + 1];
    float a = 1.f;
    for (int p = s; p < e; ++p) a += __int_as_float(pairs[p].y);
    dinv2[n] = rsqrtf(a);
}

// ======== g1 = bf16( dinv2 * (x @ W1) ) via MFMA 16x16x32 bf16 ========
__global__ __launch_bounds__(256) void k_mm1(const float* __restrict__ x,
                                             const unsigned short* __restrict__ W1t,
                                             const float* __restrict__ dinv2,
                                             unsigned short* __restrict__ gbuf, int N) {
    __shared__ __align__(16) unsigned short xb[64 * FIN];   // 16 KiB
    int tid  = threadIdx.x;
    int lane = tid & 63;
    int w    = tid >> 6;
    int lrow = lane & 15;
    int lk8  = lane >> 4;          // 0..3
    int tile0 = blockIdx.x * 64;
    if (tile0 >= N) return;
    int nrow = min(64, N - tile0);

    short8v breg[4][4];
    #pragma unroll
    for (int kk = 0; kk < 4; ++kk)
        #pragma unroll
        for (int ct = 0; ct < 4; ++ct)
            breg[kk][ct] = *(const short8v*)(W1t + (16 * ct + lrow) * FIN + kk * 32 + lk8 * 8);

    const float4* gx = (const float4*)(x + (size_t)tile0 * FIN);
    int nv = nrow * (FIN / 4);
    for (int i = tid; i < nv; i += 256) {
        float4 v = gx[i];
        int row = i >> 5;                      // FIN/4 = 32 float4 per row
        int byte = row * 256 + (i & 31) * 8;
        unsigned swz = (unsigned)(byte ^ ((row & 7) << 4));
        *(uint2*)((char*)xb + swz) = make_uint2(pack2(v.x, v.y), pack2(v.z, v.w));
    }
    __syncthreads();

    f32x4 acc[4];
    #pragma unroll
    for (int ct = 0; ct < 4; ++ct) acc[ct] = 0.f;
    int arow = 16 * w + lrow;
    #pragma unroll
    for (int kk = 0; kk < 4; ++kk) {
        int byte = arow * 256 + kk * 64 + lk8 * 16;
        unsigned swz = (unsigned)(byte ^ ((arow & 7) << 4));
        short8v a = *(const short8v*)((const char*)xb + swz);
        #pragma unroll
        for (int ct = 0; ct < 4; ++ct)
            acc[ct] = __builtin_amdgcn_mfma_f32_16x16x32_bf16(a, breg[kk][ct], acc[ct], 0, 0, 0);
    }
    #pragma unroll
    for (int i = 0; i < 4; ++i) {
        int grow = tile0 + 16 * w + lk8 * 4 + i;
        if (grow < N) {
            float sn = dinv2[grow];
            #pragma unroll
            for (int ct = 0; ct < 4; ++ct)
                gbuf[(size_t)grow * HD + 16 * ct + lrow] = f2bf(sn * acc[ct][i]);
        }
    }
}

// ======== g2 = bf16( dinv2 * (relu(agg+b1) @ W2) ) via MFMA, K=64 ========
__global__ __launch_bounds__(256) void k_mm2(const float* __restrict__ agg,
                                             const float* __restrict__ b1,
                                             const unsigned short* __restrict__ W2t,
                                             const float* __restrict__ dinv2,
                                             unsigned short* __restrict__ gbuf, int N) {
    __shared__ __align__(16) unsigned short xb[64 * HD];    // 8 KiB
    int tid  = threadIdx.x;
    int lane = tid & 63;
    int w    = tid >> 6;
    int lrow = lane & 15;
    int lk8  = lane >> 4;
    int tile0 = blockIdx.x * 64;
    if (tile0 >= N) return;
    int nrow = min(64, N - tile0);

    short8v breg[2][4];
    #pragma unroll
    for (int kk = 0; kk < 2; ++kk)
        #pragma unroll
        for (int ct = 0; ct < 4; ++ct)
            breg[kk][ct] = *(const short8v*)(W2t + (16 * ct + lrow) * HD + kk * 32 + lk8 * 8);

    const float4* gx = (const float4*)(agg + (size_t)tile0 * HD);
    const float4* bf4 = (const float4*)b1;
    int nv = nrow * (HD / 4);
    for (int i = tid; i < nv; i += 256) {
        float4 v = gx[i];
        float4 bb = bf4[i & 15];
        v.x = fmaxf(v.x + bb.x, 0.f);
        v.y = fmaxf(v.y + bb.y, 0.f);
        v.z = fmaxf(v.z + bb.z, 0.f);
        v.w = fmaxf(v.w + bb.w, 0.f);
        int row = i >> 4;                      // HD/4 = 16 float4 per row
        int byte = row * 128 + (i & 15) * 8;
        unsigned swz = (unsigned)(byte ^ ((row & 7) << 4));
        *(uint2*)((char*)xb + swz) = make_uint2(pack2(v.x, v.y), pack2(v.z, v.w));
    }
    __syncthreads();

    f32x4 acc[4];
    #pragma unroll
    for (int ct = 0; ct < 4; ++ct) acc[ct] = 0.f;
    int arow = 16 * w + lrow;
    #pragma unroll
    for (int kk = 0; kk < 2; ++kk) {
        int byte = arow * 128 + kk * 64 + lk8 * 16;
        unsigned swz = (unsigned)(byte ^ ((arow & 7) << 4));
        short8v a = *(const short8v*)((const char*)xb + swz);
        #pragma unroll
        for (int ct = 0; ct < 4; ++ct)
            acc[ct] = __builtin_amdgcn_mfma_f32_16x16x32_bf16(a, breg[kk][ct], acc[ct], 0, 0, 0);
    }
    #pragma unroll
    for (int i = 0; i < 4; ++i) {
        int grow = tile0 + 16 * w + lk8 * 4 + i;
        if (grow < N) {
            float sn = dinv2[grow];
            #pragma unroll
            for (int ct = 0; ct < 4; ++ct)
                gbuf[(size_t)grow * HD + 16 * ct + lrow] = f2bf(sn * acc[ct][i]);
        }
    }
}

// ------- CSR gather (bf16 g, int2 pairs): agg[c] = dinv2[c]*( g[c] + sum w*g[src] ) -------
__global__ __launch_bounds__(256) void k_agg(const int* __restrict__ rowptr,
                                             const int2* __restrict__ pairs,
                                             const unsigned short* __restrict__ g,
                                             const float* __restrict__ dinv2,
                                             float* __restrict__ agg, int N) {
    int lane = threadIdx.x & 63;
    int node = (blockIdx.x * 256 + threadIdx.x) >> 6;
    if (node >= N) return;
    int s = rowptr[node];
    int e = rowptr[node + 1];
    float a0 = bf2f(g[(size_t)node * HD + lane]);
    float a1 = 0.f, a2 = 0.f, a3 = 0.f;
    int p = s;
    for (; p + 4 <= e; p += 4) {
        int2 p0 = pairs[p + 0], p1 = pairs[p + 1], p2 = pairs[p + 2], p3 = pairs[p + 3];
        a0 += __int_as_float(p0.y) * bf2f(g[(size_t)p0.x * HD + lane]);
        a1 += __int_as_float(p1.y) * bf2f(g[(size_t)p1.x * HD + lane]);
        a2 += __int_as_float(p2.y) * bf2f(g[(size_t)p2.x * HD + lane]);
        a3 += __int_as_float(p3.y) * bf2f(g[(size_t)p3.x * HD + lane]);
    }
    for (; p < e; ++p) {
        int2 pr = pairs[p];
        a0 += __int_as_float(pr.y) * bf2f(g[(size_t)pr.x * HD + lane]);
    }
    agg[(size_t)node * HD + lane] = dinv2[node] * ((a0 + a1) + (a2 + a3));
}

// ---------------- out = relu(agg + b2) @ Wout + bout ----------------
__global__ __launch_bounds__(256) void k_out(const float* __restrict__ agg,
                                             const float* __restrict__ b2,
                                             const float* __restrict__ Wout,
                                             const float* __restrict__ bout,
                                             float* __restrict__ out, int N) {
    __shared__ float Wl[HD * TD];
    __shared__ float bl[HD];
    __shared__ float bo[TD];
    for (int i = threadIdx.x; i < HD * TD; i += 256) Wl[i] = Wout[i];
    if (threadIdx.x < HD) bl[threadIdx.x] = b2[threadIdx.x];
    if (threadIdx.x < TD) bo[threadIdx.x] = bout[threadIdx.x];
    __syncthreads();
    int idx = blockIdx.x * 256 + threadIdx.x;
    if (idx >= N * TD) return;
    int n = idx / TD;
    int t = idx - n * TD;
    const float* a = agg + (size_t)n * HD;
    float acc = bo[t];
    #pragma unroll 8
    for (int k = 0; k < HD; ++k)
        acc += fmaxf(a[k] + bl[k], 0.f) * Wl[k * TD + t];
    out[idx] = acc;
}

extern "C" void kernel_launch(void* const* d_in, const int* in_sizes, int n_in,
                              void* d_out, int out_size, void* d_ws, size_t ws_size,
                              hipStream_t stream) {
    const float* x    = (const float*)d_in[0];
    const int*   ei   = (const int*)d_in[1];   // harness passes integers as int32
    const float* et   = (const float*)d_in[2];
    const float* W1   = (const float*)d_in[3];
    const float* b1   = (const float*)d_in[4];
    const float* W2   = (const float*)d_in[5];
    const float* b2   = (const float*)d_in[6];
    const float* Wout = (const float*)d_in[7];
    const float* bout = (const float*)d_in[8];
    float*       out  = (float*)d_out;

    int N = in_sizes[0] / FIN;
    int E = in_sizes[2];
    int NCHUNK = (N + CHUNK - 1) / CHUNK;          // 7 for N=100K
    int NB = (N + SCAN_ELEMS - 1) / SCAN_ELEMS;    // scan blocks (98)

    // --- workspace layout, 256B-aligned regions ---
    char*  base = (char*)d_ws;
    size_t ofs  = 0;
    auto alloc = [&](size_t bytes) -> char* {
        char* p = base + ofs;
        ofs = (ofs + bytes + 255) & ~(size_t)255;
        return p;
    };
    unsigned*       tmaxb = (unsigned*)alloc(64);
    unsigned short* W1t   = (unsigned short*)alloc((size_t)FIN * HD * 2);
    unsigned short* W2t   = (unsigned short*)alloc((size_t)HD * HD * 2);
    float*    ebuf   = (float*)alloc((size_t)E * 4);        // decay
    float*    dinv   = (float*)alloc((size_t)N * 4);
    float*    dinv2  = (float*)alloc((size_t)N * 4);
    int*      hist   = (int*)alloc((size_t)N * 4);
    int*      rowptr = (int*)alloc((size_t)(N + 1) * 4);
    int*      bsum   = (int*)alloc((size_t)1024 * 4);
    int*      boff   = (int*)alloc((size_t)1024 * 4);
    size_t privBytes = (size_t)NCHUNK * SPLIT * CHUNK * 4;  // 7.34 MB
    size_t pairBytes = (size_t)E * 8;                       // 12.8 MB
    // privD dead after k_deghist_red -> alias with pairs
    char*  privA = alloc(privBytes > pairBytes ? privBytes : pairBytes);
    float* privD = (float*)privA;
    int2*  pairs = (int2*)privA;
    int*   privH = (int*)alloc(privBytes);                  // persists through k_fill
    unsigned short* gbuf = (unsigned short*)alloc((size_t)N * HD * 2);
    float* agg   = (float*)alloc((size_t)N * HD * 4);

    int bN  = (N + 255) / 256;
    int bT  = (N + 63) / 64;
    int bWN = (N * HD + 255) / 256;

    k_cvtW       <<<32,  256, 0, stream>>>(W1, W2, W1t, W2t, tmaxb);
    k_tmax       <<<256, 256, 0, stream>>>(et, tmaxb, E);
    k_deghist    <<<NCHUNK * SPLIT, 1024, 0, stream>>>(ei, et, tmaxb, ebuf, privD, privH, E, N);
    k_deghist_red<<<bN,  256, 0, stream>>>(privD, privH, dinv, hist, N);
    k_scan_a     <<<NB,  256, 0, stream>>>(hist, bsum, N);
    k_scan_b     <<<1,  1024, 0, stream>>>(bsum, boff, NB, rowptr + N);
    k_scan_c     <<<NB,  256, 0, stream>>>(hist, boff, rowptr, N);
    k_fill       <<<NCHUNK * SPLIT, 1024, 0, stream>>>(ei, ebuf, dinv, rowptr, privH, pairs, E, N);
    k_deg2       <<<bN,  256, 0, stream>>>(rowptr, pairs, dinv2, N);

    k_mm1        <<<bT,  256, 0, stream>>>(x, W1t, dinv2, gbuf, N);
    k_agg        <<<bWN, 256, 0, stream>>>(rowptr, pairs, gbuf, dinv2, agg, N);
    k_mm2        <<<bT,  256, 0, stream>>>(agg, b1, W2t, dinv2, gbuf, N);
    k_agg        <<<bWN, 256, 0, stream>>>(rowptr, pairs, gbuf, dinv2, agg, N);
    k_out        <<<(N * TD + 255) / 256, 256, 0, stream>>>(agg, b2, Wout, bout, out, N);
}

// Round 11
// 300.749 us; speedup vs baseline: 7.7854x; 1.1429x over previous
//
#include <hip/hip_runtime.h>

#define ALPHA 0.1f
#define FIN 128
#define HD 64
#define TD 10
#define SCAN_ELEMS 1024
#define CHUNK 8192            // nodes per LDS chunk (2^13)
#define CSHIFT 13
#define SPLIT 32              // edge-slices per chunk

typedef __attribute__((ext_vector_type(8))) short short8v;   // 8 bf16 (4 VGPRs)
typedef __attribute__((ext_vector_type(4))) float f32x4;

__device__ __forceinline__ unsigned short f2bf(float f) {    // RNE f32->bf16
    unsigned u = __float_as_uint(f);
    return (unsigned short)((u + 0x7FFFu + ((u >> 16) & 1u)) >> 16);
}
__device__ __forceinline__ unsigned pack2(float a, float b) {
    return (unsigned)f2bf(a) | ((unsigned)f2bf(b) << 16);
}
__device__ __forceinline__ float bf2f(unsigned short u) {
    return __uint_as_float((unsigned)u << 16);
}

// ------- convert W1/W2 -> transposed bf16 tables; also init tmax -------
__global__ __launch_bounds__(256) void k_cvtW(const float* __restrict__ W1,
                                              const float* __restrict__ W2,
                                              unsigned short* __restrict__ W1t,
                                              unsigned short* __restrict__ W2t,
                                              unsigned* tmaxb) {
    int t = blockIdx.x * 256 + threadIdx.x;
    if (t == 0) *tmaxb = 0u;
    if (t < FIN * HD) {                       // 8192
        int c = t >> 7, k = t & 127;
        W1t[t] = f2bf(W1[k * HD + c]);
    }
    if (t < HD * HD) {                        // 4096
        int c = t >> 6, k = t & 63;
        W2t[t] = f2bf(W2[k * HD + c]);
    }
}

// ---------------- max(edge_time): block-reduced, 1 atomic per block ----------------
__global__ __launch_bounds__(256) void k_tmax(const float* __restrict__ t, unsigned* tmaxb, int E) {
    __shared__ unsigned sm[4];
    unsigned m = 0u;
    for (int i = blockIdx.x * 256 + threadIdx.x; i < E; i += gridDim.x * 256)
        m = max(m, __float_as_uint(t[i]));
    #pragma unroll
    for (int off = 32; off > 0; off >>= 1)
        m = max(m, (unsigned)__shfl_down((int)m, off, 64));
    if ((threadIdx.x & 63) == 0) sm[threadIdx.x >> 6] = m;
    __syncthreads();
    if (threadIdx.x == 0) {
        m = max(max(sm[0], sm[1]), max(sm[2], sm[3]));
        atomicMax(tmaxb, m);
    }
}

// ------ chunked LDS-privatized deg(row,decay-weighted) + hist(col) ------
// grid = NCHUNK*SPLIT blocks of 1024; LDS = 64 KiB -> 2 blocks/CU.
__global__ __launch_bounds__(1024) void k_deghist(const int* __restrict__ ei,
                                                  const float* __restrict__ t,
                                                  const unsigned* __restrict__ tmaxb,
                                                  float* __restrict__ ebuf,
                                                  float* __restrict__ privD,
                                                  int* __restrict__ privH,
                                                  int E, int N) {
    __shared__ float ldsD[CHUNK];   // 32 KiB
    __shared__ int   ldsH[CHUNK];   // 32 KiB
    int c = blockIdx.x / SPLIT;
    int b = blockIdx.x - c * SPLIT;
    int base = c * CHUNK;
    for (int i = threadIdx.x; i < CHUNK; i += 1024) { ldsD[i] = 0.f; ldsH[i] = 0; }
    __syncthreads();
    float tmax = __uint_as_float(*tmaxb);
    long long e0 = (long long)E * b / SPLIT;
    long long e1 = (long long)E * (b + 1) / SPLIT;
    for (long long e = e0 + threadIdx.x; e < e1; e += 1024) {
        int r  = ei[e];
        int cc = ei[E + e];
        float d = expf(-ALPHA * (tmax - t[e]));
        if (c == 0) ebuf[e] = d;
        unsigned rr = (unsigned)(r - base);
        if (rr < CHUNK) atomicAdd(&ldsD[rr], d);
        unsigned cr = (unsigned)(cc - base);
        if (cr < CHUNK) atomicAdd(&ldsH[cr], 1);
    }
    __syncthreads();
    float* pd = privD + ((size_t)c * SPLIT + b) * CHUNK;
    int*   ph = privH + ((size_t)c * SPLIT + b) * CHUNK;
    for (int i = threadIdx.x; i < CHUNK; i += 1024) { pd[i] = ldsD[i]; ph[i] = ldsH[i]; }
}

// ------ reduce SPLIT copies -> dinv (=rsqrt(deg)), hist; privH -> per-slice EXCL prefix ------
__global__ __launch_bounds__(256) void k_deghist_red(const float* __restrict__ privD,
                                                     int* __restrict__ privH,
                                                     float* __restrict__ dinv,
                                                     int* __restrict__ hist, int N) {
    int n = blockIdx.x * 256 + threadIdx.x;
    if (n >= N) return;
    int c = n >> CSHIFT;
    int i = n & (CHUNK - 1);
    const float* pd = privD + ((size_t)c * SPLIT) * CHUNK + i;
    int*         ph = privH + ((size_t)c * SPLIT) * CHUNK + i;
    float s = 0.f; int run = 0;
    #pragma unroll 8
    for (int b = 0; b < SPLIT; ++b) {
        s += pd[(size_t)b * CHUNK];
        int t = ph[(size_t)b * CHUNK];
        ph[(size_t)b * CHUNK] = run;       // exclusive prefix within node bucket
        run += t;
    }
    dinv[n] = s > 0.f ? rsqrtf(s) : 0.f;
    hist[n] = run;
}

// ---------------- scan phase A: per-block sum of 1024-elem hist chunk ----------------
__global__ __launch_bounds__(256) void k_scan_a(const int* __restrict__ hist,
                                                int* __restrict__ bsum, int N) {
    __shared__ int sm[4];
    int base = blockIdx.x * SCAN_ELEMS + threadIdx.x * 4;
    int s = 0;
    if (base + 3 < N) {
        int4 v = *(const int4*)(hist + base);
        s = v.x + v.y + v.z + v.w;
    } else {
        for (int i = base; i < N && i < base + 4; ++i) s += hist[i];
    }
    #pragma unroll
    for (int off = 32; off > 0; off >>= 1) s += __shfl_down(s, off, 64);
    if ((threadIdx.x & 63) == 0) sm[threadIdx.x >> 6] = s;
    __syncthreads();
    if (threadIdx.x == 0) bsum[blockIdx.x] = sm[0] + sm[1] + sm[2] + sm[3];
}

// ------- scan phase B: 1 block scans <=1024 partials; writes rowptr[N]=total -------
__global__ __launch_bounds__(1024) void k_scan_b(const int* __restrict__ bsum,
                                                 int* __restrict__ boff,
                                                 int NB, int* __restrict__ rowptrN) {
    __shared__ int part[1024];
    int tid = threadIdx.x;
    int v = (tid < NB) ? bsum[tid] : 0;
    part[tid] = v;
    __syncthreads();
    for (int d = 1; d < 1024; d <<= 1) {
        int t = (tid >= d) ? part[tid - d] : 0;
        __syncthreads();
        part[tid] += t;
        __syncthreads();
    }
    if (tid < NB) boff[tid] = part[tid] - v;
    if (tid == 1023) *rowptrN = part[1023];
}

// ------- scan phase C: block-local scan + block offset -> rowptr ----------
__global__ __launch_bounds__(256) void k_scan_c(const int* __restrict__ hist,
                                                const int* __restrict__ boff,
                                                int* __restrict__ rowptr, int N) {
    __shared__ int part[256];
    int base = blockIdx.x * SCAN_ELEMS + threadIdx.x * 4;
    int vv[4] = {0, 0, 0, 0};
    if (base + 3 < N) {
        int4 v = *(const int4*)(hist + base);
        vv[0] = v.x; vv[1] = v.y; vv[2] = v.z; vv[3] = v.w;
    } else {
        for (int i = 0; i < 4; ++i) if (base + i < N) vv[i] = hist[base + i];
    }
    int s = vv[0] + vv[1] + vv[2] + vv[3];
    part[threadIdx.x] = s;
    __syncthreads();
    for (int d = 1; d < 256; d <<= 1) {
        int t = (threadIdx.x >= d) ? part[threadIdx.x - d] : 0;
        __syncthreads();
        part[threadIdx.x] += t;
        __syncthreads();
    }
    int run = boff[blockIdx.x] + part[threadIdx.x] - s;
    int pp[4];
    pp[0] = run;
    pp[1] = pp[0] + vv[0];
    pp[2] = pp[1] + vv[1];
    pp[3] = pp[2] + vv[2];
    if (base + 3 < N) {
        *(int4*)(rowptr + base) = make_int4(pp[0], pp[1], pp[2], pp[3]);
    } else {
        for (int i = 0; i < 4; ++i)
            if (base + i < N) rowptr[base + i] = pp[i];
    }
}

// ------- chunked CSR fill: packed int2 (src, w-bits), LDS cursor, no device atomics -------
__global__ __launch_bounds__(1024) void k_fill(const int* __restrict__ ei,
                                               const float* __restrict__ ebuf,
                                               const float* __restrict__ dinv,
                                               const int* __restrict__ rowptr,
                                               const int* __restrict__ privH,
                                               int2* __restrict__ pairs,
                                               int E, int N) {
    __shared__ int cur[CHUNK];      // 32 KiB
    int c = blockIdx.x / SPLIT;
    int b = blockIdx.x - c * SPLIT;
    int base = c * CHUNK;
    int lim = min(CHUNK, N - base);
    const int* ph = privH + ((size_t)c * SPLIT + b) * CHUNK;
    for (int i = threadIdx.x; i < lim; i += 1024)
        cur[i] = rowptr[base + i] + ph[i];
    __syncthreads();
    long long e0 = (long long)E * b / SPLIT;
    long long e1 = (long long)E * (b + 1) / SPLIT;
    for (long long e = e0 + threadIdx.x; e < e1; e += 1024) {
        int cc = ei[E + e];
        unsigned cr = (unsigned)(cc - base);
        if (cr < (unsigned)lim) {
            int r = ei[e];
            int pos = atomicAdd(&cur[cr], 1);   // LDS atomic, block-exclusive
            float w = dinv[r] * ebuf[e] * dinv[cc];
            pairs[pos] = make_int2(r, __float_as_int(w));
        }
    }
}

// ------- dinv2[c] = rsqrt(1 + segment_sum(w))  (no atomics) -------
__global__ __launch_bounds__(256) void k_deg2(const int* __restrict__ rowptr,
                                              const int2* __restrict__ pairs,
                                              float* __restrict__ dinv2, int N) {
    int n = blockIdx.x * 256 + threadIdx.x;
    if (n >= N) return;
    int s = rowptr[n], e = rowptr[n + 1];
    float a = 1.f;
    for (int p = s; p < e; ++p) a += __int_as_float(pairs[p].y);
    dinv2[n] = rsqrtf(a);
}

// ======== g1 = bf16( dinv2 * (x @ W1) ) via MFMA 16x16x32 bf16 ========
__global__ __launch_bounds__(256) void k_mm1(const float* __restrict__ x,
                                             const unsigned short* __restrict__ W1t,
                                             const float* __restrict__ dinv2,
                                             unsigned short* __restrict__ gbuf, int N) {
    __shared__ __align__(16) unsigned short xb[64 * FIN];   // 16 KiB
    int tid  = threadIdx.x;
    int lane = tid & 63;
    int w    = tid >> 6;
    int lrow = lane & 15;
    int lk8  = lane >> 4;          // 0..3
    int tile0 = blockIdx.x * 64;
    if (tile0 >= N) return;
    int nrow = min(64, N - tile0);

    short8v breg[4][4];
    #pragma unroll
    for (int kk = 0; kk < 4; ++kk)
        #pragma unroll
        for (int ct = 0; ct < 4; ++ct)
            breg[kk][ct] = *(const short8v*)(W1t + (16 * ct + lrow) * FIN + kk * 32 + lk8 * 8);

    const float4* gx = (const float4*)(x + (size_t)tile0 * FIN);
    int nv = nrow * (FIN / 4);
    for (int i = tid; i < nv; i += 256) {
        float4 v = gx[i];
        int row = i >> 5;                      // FIN/4 = 32 float4 per row
        int byte = row * 256 + (i & 31) * 8;
        unsigned swz = (unsigned)(byte ^ ((row & 7) << 4));
        *(uint2*)((char*)xb + swz) = make_uint2(pack2(v.x, v.y), pack2(v.z, v.w));
    }
    __syncthreads();

    f32x4 acc[4];
    #pragma unroll
    for (int ct = 0; ct < 4; ++ct) acc[ct] = 0.f;
    int arow = 16 * w + lrow;
    #pragma unroll
    for (int kk = 0; kk < 4; ++kk) {
        int byte = arow * 256 + kk * 64 + lk8 * 16;
        unsigned swz = (unsigned)(byte ^ ((arow & 7) << 4));
        short8v a = *(const short8v*)((const char*)xb + swz);
        #pragma unroll
        for (int ct = 0; ct < 4; ++ct)
            acc[ct] = __builtin_amdgcn_mfma_f32_16x16x32_bf16(a, breg[kk][ct], acc[ct], 0, 0, 0);
    }
    #pragma unroll
    for (int i = 0; i < 4; ++i) {
        int grow = tile0 + 16 * w + lk8 * 4 + i;
        if (grow < N) {
            float sn = dinv2[grow];
            #pragma unroll
            for (int ct = 0; ct < 4; ++ct)
                gbuf[(size_t)grow * HD + 16 * ct + lrow] = f2bf(sn * acc[ct][i]);
        }
    }
}

// ======== g2 = bf16( dinv2 * (relu(agg+b1) @ W2) ) via MFMA, K=64 ========
__global__ __launch_bounds__(256) void k_mm2(const float* __restrict__ agg,
                                             const float* __restrict__ b1,
                                             const unsigned short* __restrict__ W2t,
                                             const float* __restrict__ dinv2,
                                             unsigned short* __restrict__ gbuf, int N) {
    __shared__ __align__(16) unsigned short xb[64 * HD];    // 8 KiB
    int tid  = threadIdx.x;
    int lane = tid & 63;
    int w    = tid >> 6;
    int lrow = lane & 15;
    int lk8  = lane >> 4;
    int tile0 = blockIdx.x * 64;
    if (tile0 >= N) return;
    int nrow = min(64, N - tile0);

    short8v breg[2][4];
    #pragma unroll
    for (int kk = 0; kk < 2; ++kk)
        #pragma unroll
        for (int ct = 0; ct < 4; ++ct)
            breg[kk][ct] = *(const short8v*)(W2t + (16 * ct + lrow) * HD + kk * 32 + lk8 * 8);

    const float4* gx = (const float4*)(agg + (size_t)tile0 * HD);
    const float4* bf4 = (const float4*)b1;
    int nv = nrow * (HD / 4);
    for (int i = tid; i < nv; i += 256) {
        float4 v = gx[i];
        float4 bb = bf4[i & 15];
        v.x = fmaxf(v.x + bb.x, 0.f);
        v.y = fmaxf(v.y + bb.y, 0.f);
        v.z = fmaxf(v.z + bb.z, 0.f);
        v.w = fmaxf(v.w + bb.w, 0.f);
        int row = i >> 4;                      // HD/4 = 16 float4 per row
        int byte = row * 128 + (i & 15) * 8;
        unsigned swz = (unsigned)(byte ^ ((row & 7) << 4));
        *(uint2*)((char*)xb + swz) = make_uint2(pack2(v.x, v.y), pack2(v.z, v.w));
    }
    __syncthreads();

    f32x4 acc[4];
    #pragma unroll
    for (int ct = 0; ct < 4; ++ct) acc[ct] = 0.f;
    int arow = 16 * w + lrow;
    #pragma unroll
    for (int kk = 0; kk < 2; ++kk) {
        int byte = arow * 128 + kk * 64 + lk8 * 16;
        unsigned swz = (unsigned)(byte ^ ((arow & 7) << 4));
        short8v a = *(const short8v*)((const char*)xb + swz);
        #pragma unroll
        for (int ct = 0; ct < 4; ++ct)
            acc[ct] = __builtin_amdgcn_mfma_f32_16x16x32_bf16(a, breg[kk][ct], acc[ct], 0, 0, 0);
    }
    #pragma unroll
    for (int i = 0; i < 4; ++i) {
        int grow = tile0 + 16 * w + lk8 * 4 + i;
        if (grow < N) {
            float sn = dinv2[grow];
            #pragma unroll
            for (int ct = 0; ct < 4; ++ct)
                gbuf[(size_t)grow * HD + 16 * ct + lrow] = f2bf(sn * acc[ct][i]);
        }
    }
}

// ------- CSR gather (bf16 g, int2 pairs): agg[c] = dinv2[c]*( g[c] + sum w*g[src] ) -------
__global__ __launch_bounds__(256) void k_agg(const int* __restrict__ rowptr,
                                             const int2* __restrict__ pairs,
                                             const unsigned short* __restrict__ g,
                                             const float* __restrict__ dinv2,
                                             float* __restrict__ agg, int N) {
    int lane = threadIdx.x & 63;
    int node = (blockIdx.x * 256 + threadIdx.x) >> 6;
    if (node >= N) return;
    int s = rowptr[node];
    int e = rowptr[node + 1];
    float a0 = bf2f(g[(size_t)node * HD + lane]);
    float a1 = 0.f, a2 = 0.f, a3 = 0.f;
    int p = s;
    for (; p + 4 <= e; p += 4) {
        int2 p0 = pairs[p + 0], p1 = pairs[p + 1], p2 = pairs[p + 2], p3 = pairs[p + 3];
        a0 += __int_as_float(p0.y) * bf2f(g[(size_t)p0.x * HD + lane]);
        a1 += __int_as_float(p1.y) * bf2f(g[(size_t)p1.x * HD + lane]);
        a2 += __int_as_float(p2.y) * bf2f(g[(size_t)p2.x * HD + lane]);
        a3 += __int_as_float(p3.y) * bf2f(g[(size_t)p3.x * HD + lane]);
    }
    for (; p < e; ++p) {
        int2 pr = pairs[p];
        a0 += __int_as_float(pr.y) * bf2f(g[(size_t)pr.x * HD + lane]);
    }
    agg[(size_t)node * HD + lane] = dinv2[node] * ((a0 + a1) + (a2 + a3));
}

// ---------------- out = relu(agg + b2) @ Wout + bout ----------------
__global__ __launch_bounds__(256) void k_out(const float* __restrict__ agg,
                                             const float* __restrict__ b2,
                                             const float* __restrict__ Wout,
                                             const float* __restrict__ bout,
                                             float* __restrict__ out, int N) {
    __shared__ float Wl[HD * TD];
    __shared__ float bl[HD];
    __shared__ float bo[TD];
    for (int i = threadIdx.x; i < HD * TD; i += 256) Wl[i] = Wout[i];
    if (threadIdx.x < HD) bl[threadIdx.x] = b2[threadIdx.x];
    if (threadIdx.x < TD) bo[threadIdx.x] = bout[threadIdx.x];
    __syncthreads();
    int idx = blockIdx.x * 256 + threadIdx.x;
    if (idx >= N * TD) return;
    int n = idx / TD;
    int t = idx - n * TD;
    const float* a = agg + (size_t)n * HD;
    float acc = bo[t];
    #pragma unroll 8
    for (int k = 0; k < HD; ++k)
        acc += fmaxf(a[k] + bl[k], 0.f) * Wl[k * TD + t];
    out[idx] = acc;
}

extern "C" void kernel_launch(void* const* d_in, const int* in_sizes, int n_in,
                              void* d_out, int out_size, void* d_ws, size_t ws_size,
                              hipStream_t stream) {
    const float* x    = (const float*)d_in[0];
    const int*   ei   = (const int*)d_in[1];   // harness passes integers as int32
    const float* et   = (const float*)d_in[2];
    const float* W1   = (const float*)d_in[3];
    const float* b1   = (const float*)d_in[4];
    const float* W2   = (const float*)d_in[5];
    const float* b2   = (const float*)d_in[6];
    const float* Wout = (const float*)d_in[7];
    const float* bout = (const float*)d_in[8];
    float*       out  = (float*)d_out;

    int N = in_sizes[0] / FIN;
    int E = in_sizes[2];
    int NCHUNK = (N + CHUNK - 1) / CHUNK;          // 13 for N=100K
    int NB = (N + SCAN_ELEMS - 1) / SCAN_ELEMS;    // scan blocks (98)

    // --- workspace layout, 256B-aligned regions ---
    char*  base = (char*)d_ws;
    size_t ofs  = 0;
    auto alloc = [&](size_t bytes) -> char* {
        char* p = base + ofs;
        ofs = (ofs + bytes + 255) & ~(size_t)255;
        return p;
    };
    unsigned*       tmaxb = (unsigned*)alloc(64);
    unsigned short* W1t   = (unsigned short*)alloc((size_t)FIN * HD * 2);
    unsigned short* W2t   = (unsigned short*)alloc((size_t)HD * HD * 2);
    float*    ebuf   = (float*)alloc((size_t)E * 4);        // decay
    float*    dinv   = (float*)alloc((size_t)N * 4);
    float*    dinv2  = (float*)alloc((size_t)N * 4);
    int*      hist   = (int*)alloc((size_t)N * 4);
    int*      rowptr = (int*)alloc((size_t)(N + 1) * 4);
    int*      bsum   = (int*)alloc((size_t)1024 * 4);
    int*      boff   = (int*)alloc((size_t)1024 * 4);
    size_t privBytes = (size_t)NCHUNK * SPLIT * CHUNK * 4;  // 13.6 MB
    size_t pairBytes = (size_t)E * 8;                       // 12.8 MB
    // privD dead after k_deghist_red -> alias with pairs
    char*  privA = alloc(privBytes > pairBytes ? privBytes : pairBytes);
    float* privD = (float*)privA;
    int2*  pairs = (int2*)privA;
    int*   privH = (int*)alloc(privBytes);                  // persists through k_fill
    unsigned short* gbuf = (unsigned short*)alloc((size_t)N * HD * 2);
    float* agg   = (float*)alloc((size_t)N * HD * 4);

    int bN  = (N + 255) / 256;
    int bT  = (N + 63) / 64;
    int bWN = (N * HD + 255) / 256;

    k_cvtW       <<<32,  256, 0, stream>>>(W1, W2, W1t, W2t, tmaxb);
    k_tmax       <<<256, 256, 0, stream>>>(et, tmaxb, E);
    k_deghist    <<<NCHUNK * SPLIT, 1024, 0, stream>>>(ei, et, tmaxb, ebuf, privD, privH, E, N);
    k_deghist_red<<<bN,  256, 0, stream>>>(privD, privH, dinv, hist, N);
    k_scan_a     <<<NB,  256, 0, stream>>>(hist, bsum, N);
    k_scan_b     <<<1,  1024, 0, stream>>>(bsum, boff, NB, rowptr + N);
    k_scan_c     <<<NB,  256, 0, stream>>>(hist, boff, rowptr, N);
    k_fill       <<<NCHUNK * SPLIT, 1024, 0, stream>>>(ei, ebuf, dinv, rowptr, privH, pairs, E, N);
    k_deg2       <<<bN,  256, 0, stream>>>(rowptr, pairs, dinv2, N);

    k_mm1        <<<bT,  256, 0, stream>>>(x, W1t, dinv2, gbuf, N);
    k_agg        <<<bWN, 256, 0, stream>>>(rowptr, pairs, gbuf, dinv2, agg, N);
    k_mm2        <<<bT,  256, 0, stream>>>(agg, b1, W2t, dinv2, gbuf, N);
    k_agg        <<<bWN, 256, 0, stream>>>(rowptr, pairs, gbuf, dinv2, agg, N);
    k_out        <<<(N * TD + 255) / 256, 256, 0, stream>>>(agg, b2, Wout, bout, out, N);
}

// Round 12
// 279.888 us; speedup vs baseline: 8.3656x; 1.0745x over previous
//
#include <hip/hip_runtime.h>

#define ALPHA 0.1f
#define FIN 128
#define HD 64
#define TD 10
#define SCAN_ELEMS 1024
#define CHUNK 8192            // nodes per LDS chunk (2^13)
#define CSHIFT 13
#define SPLIT 32              // edge-slices per chunk

typedef __attribute__((ext_vector_type(8))) short short8v;   // 8 bf16 (4 VGPRs)
typedef __attribute__((ext_vector_type(4))) float f32x4;

__device__ __forceinline__ unsigned short f2bf(float f) {    // RNE f32->bf16
    unsigned u = __float_as_uint(f);
    return (unsigned short)((u + 0x7FFFu + ((u >> 16) & 1u)) >> 16);
}
__device__ __forceinline__ unsigned pack2(float a, float b) {
    return (unsigned)f2bf(a) | ((unsigned)f2bf(b) << 16);
}
__device__ __forceinline__ float bf2f(unsigned short u) {
    return __uint_as_float((unsigned)u << 16);
}

// ------- convert W1/W2 -> transposed bf16 tables; also init tmax -------
__global__ __launch_bounds__(256) void k_cvtW(const float* __restrict__ W1,
                                              const float* __restrict__ W2,
                                              unsigned short* __restrict__ W1t,
                                              unsigned short* __restrict__ W2t,
                                              unsigned* tmaxb) {
    int t = blockIdx.x * 256 + threadIdx.x;
    if (t == 0) *tmaxb = 0u;
    if (t < FIN * HD) {                       // 8192
        int c = t >> 7, k = t & 127;
        W1t[t] = f2bf(W1[k * HD + c]);
    }
    if (t < HD * HD) {                        // 4096
        int c = t >> 6, k = t & 63;
        W2t[t] = f2bf(W2[k * HD + c]);
    }
}

// ---------------- max(edge_time): block-reduced, 1 atomic per block ----------------
__global__ __launch_bounds__(256) void k_tmax(const float* __restrict__ t, unsigned* tmaxb, int E) {
    __shared__ unsigned sm[4];
    unsigned m = 0u;
    for (int i = blockIdx.x * 256 + threadIdx.x; i < E; i += gridDim.x * 256)
        m = max(m, __float_as_uint(t[i]));
    #pragma unroll
    for (int off = 32; off > 0; off >>= 1)
        m = max(m, (unsigned)__shfl_down((int)m, off, 64));
    if ((threadIdx.x & 63) == 0) sm[threadIdx.x >> 6] = m;
    __syncthreads();
    if (threadIdx.x == 0) {
        m = max(max(sm[0], sm[1]), max(sm[2], sm[3]));
        atomicMax(tmaxb, m);
    }
}

// ------ chunked LDS-privatized deg(row,decay-weighted) + hist(col) ------
__global__ __launch_bounds__(1024) void k_deghist(const int* __restrict__ ei,
                                                  const float* __restrict__ t,
                                                  const unsigned* __restrict__ tmaxb,
                                                  float* __restrict__ ebuf,
                                                  float* __restrict__ privD,
                                                  unsigned short* __restrict__ privH,
                                                  int E, int N) {
    __shared__ float ldsD[CHUNK];   // 32 KiB
    __shared__ int   ldsH[CHUNK];   // 32 KiB
    int c = blockIdx.x / SPLIT;
    int b = blockIdx.x - c * SPLIT;
    int base = c * CHUNK;
    for (int i = threadIdx.x; i < CHUNK; i += 1024) { ldsD[i] = 0.f; ldsH[i] = 0; }
    __syncthreads();
    float tmax = __uint_as_float(*tmaxb);
    long long e0 = (long long)E * b / SPLIT;
    long long e1 = (long long)E * (b + 1) / SPLIT;
    for (long long e = e0 + threadIdx.x; e < e1; e += 1024) {
        int r  = ei[e];
        int cc = ei[E + e];
        float d = expf(-ALPHA * (tmax - t[e]));
        if (c == 0) ebuf[e] = d;
        unsigned rr = (unsigned)(r - base);
        if (rr < CHUNK) atomicAdd(&ldsD[rr], d);
        unsigned cr = (unsigned)(cc - base);
        if (cr < CHUNK) atomicAdd(&ldsH[cr], 1);
    }
    __syncthreads();
    float*          pd = privD + ((size_t)c * SPLIT + b) * CHUNK;
    unsigned short* ph = privH + ((size_t)c * SPLIT + b) * CHUNK;
    for (int i = threadIdx.x; i < CHUNK; i += 1024) {
        pd[i] = ldsD[i];
        ph[i] = (unsigned short)ldsH[i];
    }
}

// ------ reduce SPLIT copies -> dinv (=rsqrt(deg)), hist; privH -> per-slice EXCL prefix ------
__global__ __launch_bounds__(256) void k_deghist_red(const float* __restrict__ privD,
                                                     unsigned short* __restrict__ privH,
                                                     float* __restrict__ dinv,
                                                     int* __restrict__ hist, int N) {
    int n = blockIdx.x * 256 + threadIdx.x;
    if (n >= N) return;
    int c = n >> CSHIFT;
    int i = n & (CHUNK - 1);
    const float*    pd = privD + ((size_t)c * SPLIT) * CHUNK + i;
    unsigned short* ph = privH + ((size_t)c * SPLIT) * CHUNK + i;
    float s = 0.f; int run = 0;
    #pragma unroll 8
    for (int b = 0; b < SPLIT; ++b) {
        s += pd[(size_t)b * CHUNK];
        int t = ph[(size_t)b * CHUNK];
        ph[(size_t)b * CHUNK] = (unsigned short)run;   // exclusive prefix within node bucket
        run += t;
    }
    dinv[n] = s > 0.f ? rsqrtf(s) : 0.f;
    hist[n] = run;
}

// ---------------- scan phase A: per-block sum of 1024-elem hist chunk ----------------
__global__ __launch_bounds__(256) void k_scan_a(const int* __restrict__ hist,
                                                int* __restrict__ bsum, int N) {
    __shared__ int sm[4];
    int base = blockIdx.x * SCAN_ELEMS + threadIdx.x * 4;
    int s = 0;
    if (base + 3 < N) {
        int4 v = *(const int4*)(hist + base);
        s = v.x + v.y + v.z + v.w;
    } else {
        for (int i = base; i < N && i < base + 4; ++i) s += hist[i];
    }
    #pragma unroll
    for (int off = 32; off > 0; off >>= 1) s += __shfl_down(s, off, 64);
    if ((threadIdx.x & 63) == 0) sm[threadIdx.x >> 6] = s;
    __syncthreads();
    if (threadIdx.x == 0) bsum[blockIdx.x] = sm[0] + sm[1] + sm[2] + sm[3];
}

// ------- scan phase B: 1 block scans <=1024 partials; writes rowptr[N]=total -------
__global__ __launch_bounds__(1024) void k_scan_b(const int* __restrict__ bsum,
                                                 int* __restrict__ boff,
                                                 int NB, int* __restrict__ rowptrN) {
    __shared__ int part[1024];
    int tid = threadIdx.x;
    int v = (tid < NB) ? bsum[tid] : 0;
    part[tid] = v;
    __syncthreads();
    for (int d = 1; d < 1024; d <<= 1) {
        int t = (tid >= d) ? part[tid - d] : 0;
        __syncthreads();
        part[tid] += t;
        __syncthreads();
    }
    if (tid < NB) boff[tid] = part[tid] - v;
    if (tid == 1023) *rowptrN = part[1023];
}

// ------- scan phase C: block-local scan + block offset -> rowptr ----------
__global__ __launch_bounds__(256) void k_scan_c(const int* __restrict__ hist,
                                                const int* __restrict__ boff,
                                                int* __restrict__ rowptr, int N) {
    __shared__ int part[256];
    int base = blockIdx.x * SCAN_ELEMS + threadIdx.x * 4;
    int vv[4] = {0, 0, 0, 0};
    if (base + 3 < N) {
        int4 v = *(const int4*)(hist + base);
        vv[0] = v.x; vv[1] = v.y; vv[2] = v.z; vv[3] = v.w;
    } else {
        for (int i = 0; i < 4; ++i) if (base + i < N) vv[i] = hist[base + i];
    }
    int s = vv[0] + vv[1] + vv[2] + vv[3];
    part[threadIdx.x] = s;
    __syncthreads();
    for (int d = 1; d < 256; d <<= 1) {
        int t = (threadIdx.x >= d) ? part[threadIdx.x - d] : 0;
        __syncthreads();
        part[threadIdx.x] += t;
        __syncthreads();
    }
    int run = boff[blockIdx.x] + part[threadIdx.x] - s;
    int pp[4];
    pp[0] = run;
    pp[1] = pp[0] + vv[0];
    pp[2] = pp[1] + vv[1];
    pp[3] = pp[2] + vv[2];
    if (base + 3 < N) {
        *(int4*)(rowptr + base) = make_int4(pp[0], pp[1], pp[2], pp[3]);
    } else {
        for (int i = 0; i < 4; ++i)
            if (base + i < N) rowptr[base + i] = pp[i];
    }
}

// ------- chunked CSR fill: packed int2 (src, w-bits), LDS cursor, no device atomics -------
__global__ __launch_bounds__(1024) void k_fill(const int* __restrict__ ei,
                                               const float* __restrict__ ebuf,
                                               const float* __restrict__ dinv,
                                               const int* __restrict__ rowptr,
                                               const unsigned short* __restrict__ privH,
                                               int2* __restrict__ pairs,
                                               int E, int N) {
    __shared__ int cur[CHUNK];      // 32 KiB
    int c = blockIdx.x / SPLIT;
    int b = blockIdx.x - c * SPLIT;
    int base = c * CHUNK;
    int lim = min(CHUNK, N - base);
    const unsigned short* ph = privH + ((size_t)c * SPLIT + b) * CHUNK;
    for (int i = threadIdx.x; i < lim; i += 1024)
        cur[i] = rowptr[base + i] + (int)ph[i];
    __syncthreads();
    long long e0 = (long long)E * b / SPLIT;
    long long e1 = (long long)E * (b + 1) / SPLIT;
    for (long long e = e0 + threadIdx.x; e < e1; e += 1024) {
        int cc = ei[E + e];
        unsigned cr = (unsigned)(cc - base);
        if (cr < (unsigned)lim) {
            int r = ei[e];
            int pos = atomicAdd(&cur[cr], 1);   // LDS atomic, block-exclusive
            float w = dinv[r] * ebuf[e] * dinv[cc];
            pairs[pos] = make_int2(r, __float_as_int(w));
        }
    }
}

// ------- dinv2[c] = rsqrt(1 + segment_sum(w))  (no atomics) -------
__global__ __launch_bounds__(256) void k_deg2(const int* __restrict__ rowptr,
                                              const int2* __restrict__ pairs,
                                              float* __restrict__ dinv2, int N) {
    int n = blockIdx.x * 256 + threadIdx.x;
    if (n >= N) return;
    int s = rowptr[n], e = rowptr[n + 1];
    float a = 1.f;
    for (int p = s; p < e; ++p) a += __int_as_float(pairs[p].y);
    dinv2[n] = rsqrtf(a);
}

// ======== g1 = bf16( dinv2 * (x @ W1) ) via MFMA 16x16x32 bf16 ========
__global__ __launch_bounds__(256) void k_mm1(const float* __restrict__ x,
                                             const unsigned short* __restrict__ W1t,
                                             const float* __restrict__ dinv2,
                                             unsigned short* __restrict__ gbuf, int N) {
    __shared__ __align__(16) unsigned short xb[64 * FIN];   // 16 KiB
    int tid  = threadIdx.x;
    int lane = tid & 63;
    int w    = tid >> 6;
    int lrow = lane & 15;
    int lk8  = lane >> 4;          // 0..3
    int tile0 = blockIdx.x * 64;
    if (tile0 >= N) return;
    int nrow = min(64, N - tile0);

    short8v breg[4][4];
    #pragma unroll
    for (int kk = 0; kk < 4; ++kk)
        #pragma unroll
        for (int ct = 0; ct < 4; ++ct)
            breg[kk][ct] = *(const short8v*)(W1t + (16 * ct + lrow) * FIN + kk * 32 + lk8 * 8);

    const float4* gx = (const float4*)(x + (size_t)tile0 * FIN);
    int nv = nrow * (FIN / 4);
    for (int i = tid; i < nv; i += 256) {
        float4 v = gx[i];
        int row = i >> 5;                      // FIN/4 = 32 float4 per row
        int byte = row * 256 + (i & 31) * 8;
        unsigned swz = (unsigned)(byte ^ ((row & 7) << 4));
        *(uint2*)((char*)xb + swz) = make_uint2(pack2(v.x, v.y), pack2(v.z, v.w));
    }
    __syncthreads();

    f32x4 acc[4];
    #pragma unroll
    for (int ct = 0; ct < 4; ++ct) acc[ct] = 0.f;
    int arow = 16 * w + lrow;
    #pragma unroll
    for (int kk = 0; kk < 4; ++kk) {
        int byte = arow * 256 + kk * 64 + lk8 * 16;
        unsigned swz = (unsigned)(byte ^ ((arow & 7) << 4));
        short8v a = *(const short8v*)((const char*)xb + swz);
        #pragma unroll
        for (int ct = 0; ct < 4; ++ct)
            acc[ct] = __builtin_amdgcn_mfma_f32_16x16x32_bf16(a, breg[kk][ct], acc[ct], 0, 0, 0);
    }
    #pragma unroll
    for (int i = 0; i < 4; ++i) {
        int grow = tile0 + 16 * w + lk8 * 4 + i;
        if (grow < N) {
            float sn = dinv2[grow];
            #pragma unroll
            for (int ct = 0; ct < 4; ++ct)
                gbuf[(size_t)grow * HD + 16 * ct + lrow] = f2bf(sn * acc[ct][i]);
        }
    }
}

// ======== g2 = bf16( dinv2 * (relu(agg+b1) @ W2) ) via MFMA, K=64 ========
__global__ __launch_bounds__(256) void k_mm2(const float* __restrict__ agg,
                                             const float* __restrict__ b1,
                                             const unsigned short* __restrict__ W2t,
                                             const float* __restrict__ dinv2,
                                             unsigned short* __restrict__ gbuf, int N) {
    __shared__ __align__(16) unsigned short xb[64 * HD];    // 8 KiB
    int tid  = threadIdx.x;
    int lane = tid & 63;
    int w    = tid >> 6;
    int lrow = lane & 15;
    int lk8  = lane >> 4;
    int tile0 = blockIdx.x * 64;
    if (tile0 >= N) return;
    int nrow = min(64, N - tile0);

    short8v breg[2][4];
    #pragma unroll
    for (int kk = 0; kk < 2; ++kk)
        #pragma unroll
        for (int ct = 0; ct < 4; ++ct)
            breg[kk][ct] = *(const short8v*)(W2t + (16 * ct + lrow) * HD + kk * 32 + lk8 * 8);

    const float4* gx = (const float4*)(agg + (size_t)tile0 * HD);
    const float4* bf4 = (const float4*)b1;
    int nv = nrow * (HD / 4);
    for (int i = tid; i < nv; i += 256) {
        float4 v = gx[i];
        float4 bb = bf4[i & 15];
        v.x = fmaxf(v.x + bb.x, 0.f);
        v.y = fmaxf(v.y + bb.y, 0.f);
        v.z = fmaxf(v.z + bb.z, 0.f);
        v.w = fmaxf(v.w + bb.w, 0.f);
        int row = i >> 4;                      // HD/4 = 16 float4 per row
        int byte = row * 128 + (i & 15) * 8;
        unsigned swz = (unsigned)(byte ^ ((row & 7) << 4));
        *(uint2*)((char*)xb + swz) = make_uint2(pack2(v.x, v.y), pack2(v.z, v.w));
    }
    __syncthreads();

    f32x4 acc[4];
    #pragma unroll
    for (int ct = 0; ct < 4; ++ct) acc[ct] = 0.f;
    int arow = 16 * w + lrow;
    #pragma unroll
    for (int kk = 0; kk < 2; ++kk) {
        int byte = arow * 128 + kk * 64 + lk8 * 16;
        unsigned swz = (unsigned)(byte ^ ((arow & 7) << 4));
        short8v a = *(const short8v*)((const char*)xb + swz);
        #pragma unroll
        for (int ct = 0; ct < 4; ++ct)
            acc[ct] = __builtin_amdgcn_mfma_f32_16x16x32_bf16(a, breg[kk][ct], acc[ct], 0, 0, 0);
    }
    #pragma unroll
    for (int i = 0; i < 4; ++i) {
        int grow = tile0 + 16 * w + lk8 * 4 + i;
        if (grow < N) {
            float sn = dinv2[grow];
            #pragma unroll
            for (int ct = 0; ct < 4; ++ct)
                gbuf[(size_t)grow * HD + 16 * ct + lrow] = f2bf(sn * acc[ct][i]);
        }
    }
}

// ------- CSR gather, two-phase batch-8: load 8 pairs to regs, then 8 independent gathers -------
__global__ __launch_bounds__(256) void k_agg(const int* __restrict__ rowptr,
                                             const int2* __restrict__ pairs,
                                             const unsigned short* __restrict__ g,
                                             const float* __restrict__ dinv2,
                                             float* __restrict__ agg, int N) {
    int lane = threadIdx.x & 63;
    int node = (blockIdx.x * 256 + threadIdx.x) >> 6;
    if (node >= N) return;
    int s = rowptr[node];
    int e = rowptr[node + 1];
    float a0 = bf2f(g[(size_t)node * HD + lane]);
    float a1 = 0.f, a2 = 0.f, a3 = 0.f;
    int p = s;
    for (; p + 8 <= e; p += 8) {
        int2 pr[8];
        #pragma unroll
        for (int j = 0; j < 8; ++j) pr[j] = pairs[p + j];   // phase 1: 8 indep loads
        float v[8];
        #pragma unroll
        for (int j = 0; j < 8; ++j)                          // phase 2: 8 indep gathers
            v[j] = bf2f(g[(size_t)pr[j].x * HD + lane]);
        a0 += __int_as_float(pr[0].y) * v[0] + __int_as_float(pr[4].y) * v[4];
        a1 += __int_as_float(pr[1].y) * v[1] + __int_as_float(pr[5].y) * v[5];
        a2 += __int_as_float(pr[2].y) * v[2] + __int_as_float(pr[6].y) * v[6];
        a3 += __int_as_float(pr[3].y) * v[3] + __int_as_float(pr[7].y) * v[7];
    }
    if (p + 4 <= e) {
        int2 pr[4];
        #pragma unroll
        for (int j = 0; j < 4; ++j) pr[j] = pairs[p + j];
        float v[4];
        #pragma unroll
        for (int j = 0; j < 4; ++j)
            v[j] = bf2f(g[(size_t)pr[j].x * HD + lane]);
        a0 += __int_as_float(pr[0].y) * v[0];
        a1 += __int_as_float(pr[1].y) * v[1];
        a2 += __int_as_float(pr[2].y) * v[2];
        a3 += __int_as_float(pr[3].y) * v[3];
        p += 4;
    }
    for (; p < e; ++p) {
        int2 pr = pairs[p];
        a0 += __int_as_float(pr.y) * bf2f(g[(size_t)pr.x * HD + lane]);
    }
    agg[(size_t)node * HD + lane] = dinv2[node] * ((a0 + a1) + (a2 + a3));
}

// ---------------- out = relu(agg + b2) @ Wout + bout ----------------
__global__ __launch_bounds__(256) void k_out(const float* __restrict__ agg,
                                             const float* __restrict__ b2,
                                             const float* __restrict__ Wout,
                                             const float* __restrict__ bout,
                                             float* __restrict__ out, int N) {
    __shared__ float Wl[HD * TD];
    __shared__ float bl[HD];
    __shared__ float bo[TD];
    for (int i = threadIdx.x; i < HD * TD; i += 256) Wl[i] = Wout[i];
    if (threadIdx.x < HD) bl[threadIdx.x] = b2[threadIdx.x];
    if (threadIdx.x < TD) bo[threadIdx.x] = bout[threadIdx.x];
    __syncthreads();
    int idx = blockIdx.x * 256 + threadIdx.x;
    if (idx >= N * TD) return;
    int n = idx / TD;
    int t = idx - n * TD;
    const float* a = agg + (size_t)n * HD;
    float acc = bo[t];
    #pragma unroll 8
    for (int k = 0; k < HD; ++k)
        acc += fmaxf(a[k] + bl[k], 0.f) * Wl[k * TD + t];
    out[idx] = acc;
}

extern "C" void kernel_launch(void* const* d_in, const int* in_sizes, int n_in,
                              void* d_out, int out_size, void* d_ws, size_t ws_size,
                              hipStream_t stream) {
    const float* x    = (const float*)d_in[0];
    const int*   ei   = (const int*)d_in[1];   // harness passes integers as int32
    const float* et   = (const float*)d_in[2];
    const float* W1   = (const float*)d_in[3];
    const float* b1   = (const float*)d_in[4];
    const float* W2   = (const float*)d_in[5];
    const float* b2   = (const float*)d_in[6];
    const float* Wout = (const float*)d_in[7];
    const float* bout = (const float*)d_in[8];
    float*       out  = (float*)d_out;

    int N = in_sizes[0] / FIN;
    int E = in_sizes[2];
    int NCHUNK = (N + CHUNK - 1) / CHUNK;          // 13 for N=100K
    int NB = (N + SCAN_ELEMS - 1) / SCAN_ELEMS;    // scan blocks (98)

    // --- workspace layout, 256B-aligned regions ---
    char*  base = (char*)d_ws;
    size_t ofs  = 0;
    auto alloc = [&](size_t bytes) -> char* {
        char* p = base + ofs;
        ofs = (ofs + bytes + 255) & ~(size_t)255;
        return p;
    };
    unsigned*       tmaxb = (unsigned*)alloc(64);
    unsigned short* W1t   = (unsigned short*)alloc((size_t)FIN * HD * 2);
    unsigned short* W2t   = (unsigned short*)alloc((size_t)HD * HD * 2);
    float*    ebuf   = (float*)alloc((size_t)E * 4);        // decay
    float*    dinv   = (float*)alloc((size_t)N * 4);
    float*    dinv2  = (float*)alloc((size_t)N * 4);
    int*      hist   = (int*)alloc((size_t)N * 4);
    int*      rowptr = (int*)alloc((size_t)(N + 1) * 4);
    int*      bsum   = (int*)alloc((size_t)1024 * 4);
    int*      boff   = (int*)alloc((size_t)1024 * 4);
    size_t privBytes = (size_t)NCHUNK * SPLIT * CHUNK * 4;  // 13.6 MB (privD f32)
    size_t pairBytes = (size_t)E * 8;                       // 12.8 MB
    // privD dead after k_deghist_red -> alias with pairs
    char*  privA = alloc(privBytes > pairBytes ? privBytes : pairBytes);
    float* privD = (float*)privA;
    int2*  pairs = (int2*)privA;
    unsigned short* privH = (unsigned short*)alloc(privBytes / 2);  // ushort, persists thru k_fill
    unsigned short* gbuf  = (unsigned short*)alloc((size_t)N * HD * 2);
    float* agg   = (float*)alloc((size_t)N * HD * 4);

    int bN  = (N + 255) / 256;
    int bT  = (N + 63) / 64;
    int bWN = (N * HD + 255) / 256;

    k_cvtW       <<<32,  256, 0, stream>>>(W1, W2, W1t, W2t, tmaxb);
    k_tmax       <<<256, 256, 0, stream>>>(et, tmaxb, E);
    k_deghist    <<<NCHUNK * SPLIT, 1024, 0, stream>>>(ei, et, tmaxb, ebuf, privD, privH, E, N);
    k_deghist_red<<<bN,  256, 0, stream>>>(privD, privH, dinv, hist, N);
    k_scan_a     <<<NB,  256, 0, stream>>>(hist, bsum, N);
    k_scan_b     <<<1,  1024, 0, stream>>>(bsum, boff, NB, rowptr + N);
    k_scan_c     <<<NB,  256, 0, stream>>>(hist, boff, rowptr, N);
    k_fill       <<<NCHUNK * SPLIT, 1024, 0, stream>>>(ei, ebuf, dinv, rowptr, privH, pairs, E, N);
    k_deg2       <<<bN,  256, 0, stream>>>(rowptr, pairs, dinv2, N);

    k_mm1        <<<bT,  256, 0, stream>>>(x, W1t, dinv2, gbuf, N);
    k_agg        <<<bWN, 256, 0, stream>>>(rowptr, pairs, gbuf, dinv2, agg, N);
    k_mm2        <<<bT,  256, 0, stream>>>(agg, b1, W2t, dinv2, gbuf, N);
    k_agg        <<<bWN, 256, 0, stream>>>(rowptr, pairs, gbuf, dinv2, agg, N);
    k_out        <<<(N * TD + 255) / 256, 256, 0, stream>>>(agg, b2, Wout, bout, out, N);
}

// Round 13
// 279.602 us; speedup vs baseline: 8.3742x; 1.0010x over previous
//
#include <hip/hip_runtime.h>

#define ALPHA 0.1f
#define FIN 128
#define HD 64
#define TD 10
#define SCAN_ELEMS 1024
#define CHUNK 8192            // nodes per LDS chunk (2^13)
#define CSHIFT 13
#define SPLIT 32              // edge-slices per chunk

typedef __attribute__((ext_vector_type(8))) short short8v;   // 8 bf16 (4 VGPRs)
typedef __attribute__((ext_vector_type(4))) float f32x4;

__device__ __forceinline__ unsigned short f2bf(float f) {    // RNE f32->bf16
    unsigned u = __float_as_uint(f);
    return (unsigned short)((u + 0x7FFFu + ((u >> 16) & 1u)) >> 16);
}
__device__ __forceinline__ unsigned pack2(float a, float b) {
    return (unsigned)f2bf(a) | ((unsigned)f2bf(b) << 16);
}
__device__ __forceinline__ float bf2f(unsigned short u) {
    return __uint_as_float((unsigned)u << 16);
}

// ------- convert W1/W2 -> transposed bf16 tables; also init tmax -------
__global__ __launch_bounds__(256) void k_cvtW(const float* __restrict__ W1,
                                              const float* __restrict__ W2,
                                              unsigned short* __restrict__ W1t,
                                              unsigned short* __restrict__ W2t,
                                              unsigned* tmaxb) {
    int t = blockIdx.x * 256 + threadIdx.x;
    if (t == 0) *tmaxb = 0u;
    if (t < FIN * HD) {                       // 8192
        int c = t >> 7, k = t & 127;
        W1t[t] = f2bf(W1[k * HD + c]);
    }
    if (t < HD * HD) {                        // 4096
        int c = t >> 6, k = t & 63;
        W2t[t] = f2bf(W2[k * HD + c]);
    }
}

// ---------------- max(edge_time): block-reduced, 1 atomic per block ----------------
__global__ __launch_bounds__(256) void k_tmax(const float* __restrict__ t, unsigned* tmaxb, int E) {
    __shared__ unsigned sm[4];
    unsigned m = 0u;
    for (int i = blockIdx.x * 256 + threadIdx.x; i < E; i += gridDim.x * 256)
        m = max(m, __float_as_uint(t[i]));
    #pragma unroll
    for (int off = 32; off > 0; off >>= 1)
        m = max(m, (unsigned)__shfl_down((int)m, off, 64));
    if ((threadIdx.x & 63) == 0) sm[threadIdx.x >> 6] = m;
    __syncthreads();
    if (threadIdx.x == 0) {
        m = max(max(sm[0], sm[1]), max(sm[2], sm[3]));
        atomicMax(tmaxb, m);
    }
}

// ------ chunked LDS-privatized deg(row,decay-weighted) + hist(col) ------
__global__ __launch_bounds__(1024) void k_deghist(const int* __restrict__ ei,
                                                  const float* __restrict__ t,
                                                  const unsigned* __restrict__ tmaxb,
                                                  float* __restrict__ ebuf,
                                                  float* __restrict__ privD,
                                                  unsigned short* __restrict__ privH,
                                                  int E, int N) {
    __shared__ float ldsD[CHUNK];   // 32 KiB
    __shared__ int   ldsH[CHUNK];   // 32 KiB
    int c = blockIdx.x / SPLIT;
    int b = blockIdx.x - c * SPLIT;
    int base = c * CHUNK;
    for (int i = threadIdx.x; i < CHUNK; i += 1024) { ldsD[i] = 0.f; ldsH[i] = 0; }
    __syncthreads();
    float tmax = __uint_as_float(*tmaxb);
    long long e0 = (long long)E * b / SPLIT;
    long long e1 = (long long)E * (b + 1) / SPLIT;
    for (long long e = e0 + threadIdx.x; e < e1; e += 1024) {
        int r  = ei[e];
        int cc = ei[E + e];
        float d = expf(-ALPHA * (tmax - t[e]));
        if (c == 0) ebuf[e] = d;
        unsigned rr = (unsigned)(r - base);
        if (rr < CHUNK) atomicAdd(&ldsD[rr], d);
        unsigned cr = (unsigned)(cc - base);
        if (cr < CHUNK) atomicAdd(&ldsH[cr], 1);
    }
    __syncthreads();
    float*          pd = privD + ((size_t)c * SPLIT + b) * CHUNK;
    unsigned short* ph = privH + ((size_t)c * SPLIT + b) * CHUNK;
    for (int i = threadIdx.x; i < CHUNK; i += 1024) {
        pd[i] = ldsD[i];
        ph[i] = (unsigned short)ldsH[i];
    }
}

// ------ reduce SPLIT copies -> dinv (=rsqrt(deg)), hist; privH -> per-slice EXCL prefix ------
__global__ __launch_bounds__(256) void k_deghist_red(const float* __restrict__ privD,
                                                     unsigned short* __restrict__ privH,
                                                     float* __restrict__ dinv,
                                                     int* __restrict__ hist, int N) {
    int n = blockIdx.x * 256 + threadIdx.x;
    if (n >= N) return;
    int c = n >> CSHIFT;
    int i = n & (CHUNK - 1);
    const float*    pd = privD + ((size_t)c * SPLIT) * CHUNK + i;
    unsigned short* ph = privH + ((size_t)c * SPLIT) * CHUNK + i;
    float s = 0.f; int run = 0;
    #pragma unroll 8
    for (int b = 0; b < SPLIT; ++b) {
        s += pd[(size_t)b * CHUNK];
        int t = ph[(size_t)b * CHUNK];
        ph[(size_t)b * CHUNK] = (unsigned short)run;   // exclusive prefix within node bucket
        run += t;
    }
    dinv[n] = s > 0.f ? rsqrtf(s) : 0.f;
    hist[n] = run;
}

// ---------------- scan phase A: per-block sum of 1024-elem hist chunk ----------------
__global__ __launch_bounds__(256) void k_scan_a(const int* __restrict__ hist,
                                                int* __restrict__ bsum, int N) {
    __shared__ int sm[4];
    int base = blockIdx.x * SCAN_ELEMS + threadIdx.x * 4;
    int s = 0;
    if (base + 3 < N) {
        int4 v = *(const int4*)(hist + base);
        s = v.x + v.y + v.z + v.w;
    } else {
        for (int i = base; i < N && i < base + 4; ++i) s += hist[i];
    }
    #pragma unroll
    for (int off = 32; off > 0; off >>= 1) s += __shfl_down(s, off, 64);
    if ((threadIdx.x & 63) == 0) sm[threadIdx.x >> 6] = s;
    __syncthreads();
    if (threadIdx.x == 0) bsum[blockIdx.x] = sm[0] + sm[1] + sm[2] + sm[3];
}

// ------- scan phase B: 1 block scans <=1024 partials; writes rowptr[N]=total -------
__global__ __launch_bounds__(1024) void k_scan_b(const int* __restrict__ bsum,
                                                 int* __restrict__ boff,
                                                 int NB, int* __restrict__ rowptrN) {
    __shared__ int part[1024];
    int tid = threadIdx.x;
    int v = (tid < NB) ? bsum[tid] : 0;
    part[tid] = v;
    __syncthreads();
    for (int d = 1; d < 1024; d <<= 1) {
        int t = (tid >= d) ? part[tid - d] : 0;
        __syncthreads();
        part[tid] += t;
        __syncthreads();
    }
    if (tid < NB) boff[tid] = part[tid] - v;
    if (tid == 1023) *rowptrN = part[1023];
}

// ------- scan phase C: block-local scan + block offset -> rowptr ----------
__global__ __launch_bounds__(256) void k_scan_c(const int* __restrict__ hist,
                                                const int* __restrict__ boff,
                                                int* __restrict__ rowptr, int N) {
    __shared__ int part[256];
    int base = blockIdx.x * SCAN_ELEMS + threadIdx.x * 4;
    int vv[4] = {0, 0, 0, 0};
    if (base + 3 < N) {
        int4 v = *(const int4*)(hist + base);
        vv[0] = v.x; vv[1] = v.y; vv[2] = v.z; vv[3] = v.w;
    } else {
        for (int i = 0; i < 4; ++i) if (base + i < N) vv[i] = hist[base + i];
    }
    int s = vv[0] + vv[1] + vv[2] + vv[3];
    part[threadIdx.x] = s;
    __syncthreads();
    for (int d = 1; d < 256; d <<= 1) {
        int t = (threadIdx.x >= d) ? part[threadIdx.x - d] : 0;
        __syncthreads();
        part[threadIdx.x] += t;
        __syncthreads();
    }
    int run = boff[blockIdx.x] + part[threadIdx.x] - s;
    int pp[4];
    pp[0] = run;
    pp[1] = pp[0] + vv[0];
    pp[2] = pp[1] + vv[1];
    pp[3] = pp[2] + vv[2];
    if (base + 3 < N) {
        *(int4*)(rowptr + base) = make_int4(pp[0], pp[1], pp[2], pp[3]);
    } else {
        for (int i = 0; i < 4; ++i)
            if (base + i < N) rowptr[base + i] = pp[i];
    }
}

// ------- chunked CSR fill: packed int2 (src, w-bits), LDS cursor, no device atomics -------
__global__ __launch_bounds__(1024) void k_fill(const int* __restrict__ ei,
                                               const float* __restrict__ ebuf,
                                               const float* __restrict__ dinv,
                                               const int* __restrict__ rowptr,
                                               const unsigned short* __restrict__ privH,
                                               int2* __restrict__ pairs,
                                               int E, int N) {
    __shared__ int cur[CHUNK];      // 32 KiB
    int c = blockIdx.x / SPLIT;
    int b = blockIdx.x - c * SPLIT;
    int base = c * CHUNK;
    int lim = min(CHUNK, N - base);
    const unsigned short* ph = privH + ((size_t)c * SPLIT + b) * CHUNK;
    for (int i = threadIdx.x; i < lim; i += 1024)
        cur[i] = rowptr[base + i] + (int)ph[i];
    __syncthreads();
    long long e0 = (long long)E * b / SPLIT;
    long long e1 = (long long)E * (b + 1) / SPLIT;
    for (long long e = e0 + threadIdx.x; e < e1; e += 1024) {
        int cc = ei[E + e];
        unsigned cr = (unsigned)(cc - base);
        if (cr < (unsigned)lim) {
            int r = ei[e];
            int pos = atomicAdd(&cur[cr], 1);   // LDS atomic, block-exclusive
            float w = dinv[r] * ebuf[e] * dinv[cc];
            pairs[pos] = make_int2(r, __float_as_int(w));
        }
    }
}

// ------- dinv2[c] = rsqrt(1 + segment_sum(w))  (no atomics) -------
__global__ __launch_bounds__(256) void k_deg2(const int* __restrict__ rowptr,
                                              const int2* __restrict__ pairs,
                                              float* __restrict__ dinv2, int N) {
    int n = blockIdx.x * 256 + threadIdx.x;
    if (n >= N) return;
    int s = rowptr[n], e = rowptr[n + 1];
    float a = 1.f;
    for (int p = s; p < e; ++p) a += __int_as_float(pairs[p].y);
    dinv2[n] = rsqrtf(a);
}

// ======== g1 = bf16( dinv2 * (x @ W1) ) via MFMA 16x16x32 bf16 ========
__global__ __launch_bounds__(256) void k_mm1(const float* __restrict__ x,
                                             const unsigned short* __restrict__ W1t,
                                             const float* __restrict__ dinv2,
                                             unsigned short* __restrict__ gbuf, int N) {
    __shared__ __align__(16) unsigned short xb[64 * FIN];   // 16 KiB
    int tid  = threadIdx.x;
    int lane = tid & 63;
    int w    = tid >> 6;
    int lrow = lane & 15;
    int lk8  = lane >> 4;          // 0..3
    int tile0 = blockIdx.x * 64;
    if (tile0 >= N) return;
    int nrow = min(64, N - tile0);

    short8v breg[4][4];
    #pragma unroll
    for (int kk = 0; kk < 4; ++kk)
        #pragma unroll
        for (int ct = 0; ct < 4; ++ct)
            breg[kk][ct] = *(const short8v*)(W1t + (16 * ct + lrow) * FIN + kk * 32 + lk8 * 8);

    const float4* gx = (const float4*)(x + (size_t)tile0 * FIN);
    int nv = nrow * (FIN / 4);
    for (int i = tid; i < nv; i += 256) {
        float4 v = gx[i];
        int row = i >> 5;                      // FIN/4 = 32 float4 per row
        int byte = row * 256 + (i & 31) * 8;
        unsigned swz = (unsigned)(byte ^ ((row & 7) << 4));
        *(uint2*)((char*)xb + swz) = make_uint2(pack2(v.x, v.y), pack2(v.z, v.w));
    }
    __syncthreads();

    f32x4 acc[4];
    #pragma unroll
    for (int ct = 0; ct < 4; ++ct) acc[ct] = 0.f;
    int arow = 16 * w + lrow;
    #pragma unroll
    for (int kk = 0; kk < 4; ++kk) {
        int byte = arow * 256 + kk * 64 + lk8 * 16;
        unsigned swz = (unsigned)(byte ^ ((arow & 7) << 4));
        short8v a = *(const short8v*)((const char*)xb + swz);
        #pragma unroll
        for (int ct = 0; ct < 4; ++ct)
            acc[ct] = __builtin_amdgcn_mfma_f32_16x16x32_bf16(a, breg[kk][ct], acc[ct], 0, 0, 0);
    }
    #pragma unroll
    for (int i = 0; i < 4; ++i) {
        int grow = tile0 + 16 * w + lk8 * 4 + i;
        if (grow < N) {
            float sn = dinv2[grow];
            #pragma unroll
            for (int ct = 0; ct < 4; ++ct)
                gbuf[(size_t)grow * HD + 16 * ct + lrow] = f2bf(sn * acc[ct][i]);
        }
    }
}

// ======== g2 = bf16( dinv2 * (relu(agg+b1) @ W2) ) via MFMA, K=64 ========
__global__ __launch_bounds__(256) void k_mm2(const float* __restrict__ agg,
                                             const float* __restrict__ b1,
                                             const unsigned short* __restrict__ W2t,
                                             const float* __restrict__ dinv2,
                                             unsigned short* __restrict__ gbuf, int N) {
    __shared__ __align__(16) unsigned short xb[64 * HD];    // 8 KiB
    int tid  = threadIdx.x;
    int lane = tid & 63;
    int w    = tid >> 6;
    int lrow = lane & 15;
    int lk8  = lane >> 4;
    int tile0 = blockIdx.x * 64;
    if (tile0 >= N) return;
    int nrow = min(64, N - tile0);

    short8v breg[2][4];
    #pragma unroll
    for (int kk = 0; kk < 2; ++kk)
        #pragma unroll
        for (int ct = 0; ct < 4; ++ct)
            breg[kk][ct] = *(const short8v*)(W2t + (16 * ct + lrow) * HD + kk * 32 + lk8 * 8);

    const float4* gx = (const float4*)(agg + (size_t)tile0 * HD);
    const float4* bf4 = (const float4*)b1;
    int nv = nrow * (HD / 4);
    for (int i = tid; i < nv; i += 256) {
        float4 v = gx[i];
        float4 bb = bf4[i & 15];
        v.x = fmaxf(v.x + bb.x, 0.f);
        v.y = fmaxf(v.y + bb.y, 0.f);
        v.z = fmaxf(v.z + bb.z, 0.f);
        v.w = fmaxf(v.w + bb.w, 0.f);
        int row = i >> 4;                      // HD/4 = 16 float4 per row
        int byte = row * 128 + (i & 15) * 8;
        unsigned swz = (unsigned)(byte ^ ((row & 7) << 4));
        *(uint2*)((char*)xb + swz) = make_uint2(pack2(v.x, v.y), pack2(v.z, v.w));
    }
    __syncthreads();

    f32x4 acc[4];
    #pragma unroll
    for (int ct = 0; ct < 4; ++ct) acc[ct] = 0.f;
    int arow = 16 * w + lrow;
    #pragma unroll
    for (int kk = 0; kk < 2; ++kk) {
        int byte = arow * 128 + kk * 64 + lk8 * 16;
        unsigned swz = (unsigned)(byte ^ ((arow & 7) << 4));
        short8v a = *(const short8v*)((const char*)xb + swz);
        #pragma unroll
        for (int ct = 0; ct < 4; ++ct)
            acc[ct] = __builtin_amdgcn_mfma_f32_16x16x32_bf16(a, breg[kk][ct], acc[ct], 0, 0, 0);
    }
    #pragma unroll
    for (int i = 0; i < 4; ++i) {
        int grow = tile0 + 16 * w + lk8 * 4 + i;
        if (grow < N) {
            float sn = dinv2[grow];
            #pragma unroll
            for (int ct = 0; ct < 4; ++ct)
                gbuf[(size_t)grow * HD + 16 * ct + lrow] = f2bf(sn * acc[ct][i]);
        }
    }
}

// ------- CSR gather, software-pipelined batch-8: load batch i+1 pairs while gathering batch i -------
__global__ __launch_bounds__(256) void k_agg(const int* __restrict__ rowptr,
                                             const int2* __restrict__ pairs,
                                             const unsigned short* __restrict__ g,
                                             const float* __restrict__ dinv2,
                                             float* __restrict__ agg, int N) {
    int lane = threadIdx.x & 63;
    int node = (blockIdx.x * 256 + threadIdx.x) >> 6;
    if (node >= N) return;
    int s = rowptr[node];
    int e = rowptr[node + 1];
    float a0 = bf2f(g[(size_t)node * HD + lane]);
    float a1 = 0.f, a2 = 0.f, a3 = 0.f;
    int p = s;
    int nb = (e - s) >> 3;                       // full 8-batches
    if (nb > 0) {
        int2 prA[8], prB[8];
        #pragma unroll
        for (int j = 0; j < 8; ++j) prA[j] = pairs[p + j];       // prologue
        for (int b = 0; b < nb; ++b) {
            if (b + 1 < nb) {
                #pragma unroll
                for (int j = 0; j < 8; ++j) prB[j] = pairs[p + 8 + j];   // prefetch next
            }
            float v[8];
            #pragma unroll
            for (int j = 0; j < 8; ++j)                          // 8 indep gathers
                v[j] = bf2f(g[(size_t)prA[j].x * HD + lane]);
            a0 += __int_as_float(prA[0].y) * v[0] + __int_as_float(prA[4].y) * v[4];
            a1 += __int_as_float(prA[1].y) * v[1] + __int_as_float(prA[5].y) * v[5];
            a2 += __int_as_float(prA[2].y) * v[2] + __int_as_float(prA[6].y) * v[6];
            a3 += __int_as_float(prA[3].y) * v[3] + __int_as_float(prA[7].y) * v[7];
            #pragma unroll
            for (int j = 0; j < 8; ++j) prA[j] = prB[j];         // rotate buffers
            p += 8;
        }
    }
    if (p + 4 <= e) {
        int2 pr[4];
        #pragma unroll
        for (int j = 0; j < 4; ++j) pr[j] = pairs[p + j];
        float v[4];
        #pragma unroll
        for (int j = 0; j < 4; ++j)
            v[j] = bf2f(g[(size_t)pr[j].x * HD + lane]);
        a0 += __int_as_float(pr[0].y) * v[0];
        a1 += __int_as_float(pr[1].y) * v[1];
        a2 += __int_as_float(pr[2].y) * v[2];
        a3 += __int_as_float(pr[3].y) * v[3];
        p += 4;
    }
    for (; p < e; ++p) {
        int2 pr = pairs[p];
        a0 += __int_as_float(pr.y) * bf2f(g[(size_t)pr.x * HD + lane]);
    }
    agg[(size_t)node * HD + lane] = dinv2[node] * ((a0 + a1) + (a2 + a3));
}

// ---------------- out = relu(agg + b2) @ Wout + bout ----------------
__global__ __launch_bounds__(256) void k_out(const float* __restrict__ agg,
                                             const float* __restrict__ b2,
                                             const float* __restrict__ Wout,
                                             const float* __restrict__ bout,
                                             float* __restrict__ out, int N) {
    __shared__ float Wl[HD * TD];
    __shared__ float bl[HD];
    __shared__ float bo[TD];
    for (int i = threadIdx.x; i < HD * TD; i += 256) Wl[i] = Wout[i];
    if (threadIdx.x < HD) bl[threadIdx.x] = b2[threadIdx.x];
    if (threadIdx.x < TD) bo[threadIdx.x] = bout[threadIdx.x];
    __syncthreads();
    int idx = blockIdx.x * 256 + threadIdx.x;
    if (idx >= N * TD) return;
    int n = idx / TD;
    int t = idx - n * TD;
    const float* a = agg + (size_t)n * HD;
    float acc = bo[t];
    #pragma unroll 8
    for (int k = 0; k < HD; ++k)
        acc += fmaxf(a[k] + bl[k], 0.f) * Wl[k * TD + t];
    out[idx] = acc;
}

extern "C" void kernel_launch(void* const* d_in, const int* in_sizes, int n_in,
                              void* d_out, int out_size, void* d_ws, size_t ws_size,
                              hipStream_t stream) {
    const float* x    = (const float*)d_in[0];
    const int*   ei   = (const int*)d_in[1];   // harness passes integers as int32
    const float* et   = (const float*)d_in[2];
    const float* W1   = (const float*)d_in[3];
    const float* b1   = (const float*)d_in[4];
    const float* W2   = (const float*)d_in[5];
    const float* b2   = (const float*)d_in[6];
    const float* Wout = (const float*)d_in[7];
    const float* bout = (const float*)d_in[8];
    float*       out  = (float*)d_out;

    int N = in_sizes[0] / FIN;
    int E = in_sizes[2];
    int NCHUNK = (N + CHUNK - 1) / CHUNK;          // 13 for N=100K
    int NB = (N + SCAN_ELEMS - 1) / SCAN_ELEMS;    // scan blocks (98)

    // --- workspace layout, 256B-aligned regions ---
    char*  base = (char*)d_ws;
    size_t ofs  = 0;
    auto alloc = [&](size_t bytes) -> char* {
        char* p = base + ofs;
        ofs = (ofs + bytes + 255) & ~(size_t)255;
        return p;
    };
    unsigned*       tmaxb = (unsigned*)alloc(64);
    unsigned short* W1t   = (unsigned short*)alloc((size_t)FIN * HD * 2);
    unsigned short* W2t   = (unsigned short*)alloc((size_t)HD * HD * 2);
    float*    ebuf   = (float*)alloc((size_t)E * 4);        // decay
    float*    dinv   = (float*)alloc((size_t)N * 4);
    float*    dinv2  = (float*)alloc((size_t)N * 4);
    int*      hist   = (int*)alloc((size_t)N * 4);
    int*      rowptr = (int*)alloc((size_t)(N + 1) * 4);
    int*      bsum   = (int*)alloc((size_t)1024 * 4);
    int*      boff   = (int*)alloc((size_t)1024 * 4);
    size_t privBytes = (size_t)NCHUNK * SPLIT * CHUNK * 4;  // 13.6 MB (privD f32)
    size_t pairBytes = (size_t)E * 8;                       // 12.8 MB
    // privD dead after k_deghist_red -> alias with pairs
    char*  privA = alloc(privBytes > pairBytes ? privBytes : pairBytes);
    float* privD = (float*)privA;
    int2*  pairs = (int2*)privA;
    unsigned short* privH = (unsigned short*)alloc(privBytes / 2);  // ushort, persists thru k_fill
    unsigned short* gbuf  = (unsigned short*)alloc((size_t)N * HD * 2);
    float* agg   = (float*)alloc((size_t)N * HD * 4);

    int bN  = (N + 255) / 256;
    int bT  = (N + 63) / 64;
    int bWN = (N * HD + 255) / 256;

    k_cvtW       <<<32,  256, 0, stream>>>(W1, W2, W1t, W2t, tmaxb);
    k_tmax       <<<256, 256, 0, stream>>>(et, tmaxb, E);
    k_deghist    <<<NCHUNK * SPLIT, 1024, 0, stream>>>(ei, et, tmaxb, ebuf, privD, privH, E, N);
    k_deghist_red<<<bN,  256, 0, stream>>>(privD, privH, dinv, hist, N);
    k_scan_a     <<<NB,  256, 0, stream>>>(hist, bsum, N);
    k_scan_b     <<<1,  1024, 0, stream>>>(bsum, boff, NB, rowptr + N);
    k_scan_c     <<<NB,  256, 0, stream>>>(hist, boff, rowptr, N);
    k_fill       <<<NCHUNK * SPLIT, 1024, 0, stream>>>(ei, ebuf, dinv, rowptr, privH, pairs, E, N);
    k_deg2       <<<bN,  256, 0, stream>>>(rowptr, pairs, dinv2, N);

    k_mm1        <<<bT,  256, 0, stream>>>(x, W1t, dinv2, gbuf, N);
    k_agg        <<<bWN, 256, 0, stream>>>(rowptr, pairs, gbuf, dinv2, agg, N);
    k_mm2        <<<bT,  256, 0, stream>>>(agg, b1, W2t, dinv2, gbuf, N);
    k_agg        <<<bWN, 256, 0, stream>>>(rowptr, pairs, gbuf, dinv2, agg, N);
    k_out        <<<(N * TD + 255) / 256, 256, 0, stream>>>(agg, b2, Wout, bout, out, N);
}